// Round 3
// baseline (1528.511 us; speedup 1.0000x reference)
//
#include <hip/hip_runtime.h>
#include <math.h>

#define N_NODES 50000
#define N_EDGES 800000
#define D 128
#define N_GRAPHS 64
#define EPS 1e-5f
#define PCHUNK 16

static inline size_t align256(size_t x) { return (x + 255) & ~(size_t)255; }

// ---------------- GEMM: K,Q,V,S = X @ [Wk|Wq|Wv|Ws] + biases ----------------
// grid: N/16 blocks, 256 threads. Each block computes 16 rows x 512 cols.
// Threads 0..127 compute K,Q columns; threads 128..255 compute V,S columns.
__global__ void gemm_kqvs(const float* __restrict__ X,
                          const float* __restrict__ Wk, const float* __restrict__ bk,
                          const float* __restrict__ Wq, const float* __restrict__ bq,
                          const float* __restrict__ Wv, const float* __restrict__ bv,
                          const float* __restrict__ Ws, const float* __restrict__ bs,
                          float* __restrict__ Kb, float* __restrict__ Qb,
                          float* __restrict__ Vb, float* __restrict__ Sb)
{
    __shared__ float xs[16][D];
    const int tid = threadIdx.x;
    const int j = tid & 127;             // output column
    const int half = tid >> 7;           // 0: K,Q   1: V,S
    const int n0 = blockIdx.x * 16;
    for (int idx = tid; idx < 16 * D; idx += 256) {
        xs[idx >> 7][idx & 127] = X[(size_t)(n0 + (idx >> 7)) * D + (idx & 127)];
    }
    __syncthreads();
    const float* WA = half ? Wv : Wk;
    const float* WB = half ? Ws : Wq;
    float accA[16], accB[16];
    #pragma unroll
    for (int r = 0; r < 16; ++r) { accA[r] = 0.f; accB[r] = 0.f; }
    #pragma unroll 4
    for (int k = 0; k < D; ++k) {
        const float wa = WA[k * D + j];
        const float wb = WB[k * D + j];
        #pragma unroll
        for (int r = 0; r < 16; ++r) {
            const float xv = xs[r][k];
            accA[r] = fmaf(xv, wa, accA[r]);
            accB[r] = fmaf(xv, wb, accB[r]);
        }
    }
    const float bA = half ? bv[j] : bk[j];
    const float bB = half ? bs[j] : bq[j];
    float* OA = half ? Vb : Kb;
    float* OB = half ? Sb : Qb;
    #pragma unroll
    for (int r = 0; r < 16; ++r) {
        const size_t n = (size_t)(n0 + r);
        OA[n * D + j] = accA[r] + bA;
        OB[n * D + j] = accB[r] + bB;
    }
}

// ---------------- CSR build ----------------
__global__ void hist_dst(const int* __restrict__ dst, int* __restrict__ cnt) {
    int e = blockIdx.x * blockDim.x + threadIdx.x;
    if (e < N_EDGES) atomicAdd(&cnt[dst[e]], 1);
}

// exclusive scan over cnt -> row_start AND cursor (both get the same values)
__global__ void scan_rows(const int* __restrict__ cnt, int* __restrict__ row_start,
                          int* __restrict__ cursor) {
    __shared__ int partial[1024];
    const int T = 1024;
    const int t = threadIdx.x;
    const int chunk = (N_NODES + T - 1) / T;
    const int lo = t * chunk;
    const int hi = min(lo + chunk, N_NODES);
    int s = 0;
    for (int i = lo; i < hi; ++i) s += cnt[i];
    partial[t] = s;
    __syncthreads();
    for (int off = 1; off < T; off <<= 1) {
        int add = (t >= off) ? partial[t - off] : 0;
        __syncthreads();
        partial[t] += add;
        __syncthreads();
    }
    int base = (t == 0) ? 0 : partial[t - 1];
    for (int i = lo; i < hi; ++i) {
        row_start[i] = base;
        cursor[i] = base;
        base += cnt[i];
    }
    if (t == T - 1) { row_start[N_NODES] = partial[T - 1]; cursor[N_NODES] = partial[T - 1]; }
}

__global__ void fill_csr(const int* __restrict__ src, const int* __restrict__ dst,
                         int* __restrict__ cursor, int* __restrict__ col) {
    int e = blockIdx.x * blockDim.x + threadIdx.x;
    if (e < N_EDGES) {
        int d = dst[e];
        int p = atomicAdd(&cursor[d], 1);
        col[p] = src[e];
    }
}

// ---------------- Edge aggregation + skip + ReLU ----------------
// block 256 threads = 2 dst nodes; thread handles one feature dim.
__global__ void aggregate(const float* __restrict__ Kb, const float* __restrict__ Qb,
                          const float* __restrict__ Vb, const float* __restrict__ Sb,
                          const int* __restrict__ row_start, const int* __restrict__ col,
                          float* __restrict__ H)
{
    const int tid = threadIdx.x;
    const int node = blockIdx.x * 2 + (tid >> 7);
    const int d = tid & 127;
    const float kd = Kb[(size_t)node * D + d];
    float acc = 0.f;
    const int e0 = row_start[node];
    const int e1 = row_start[node + 1];
    for (int e = e0; e < e1; ++e) {
        const int s = col[e];
        const float qd = Qb[(size_t)s * D + d];
        const float vd = Vb[(size_t)s * D + d];
        const float z = kd + qd;
        const float gate = 1.0f / (1.0f + __expf(-z));
        acc = fmaf(gate, vd, acc);
    }
    H[(size_t)node * D + d] = fmaxf(acc + Sb[(size_t)node * D + d], 0.0f);
}

// ---------------- BatchNorm over nodes ----------------
__global__ void bn_stats(const float* __restrict__ H, float* __restrict__ fsum,
                         float* __restrict__ fsq)
{
    __shared__ float s1[256], s2[256];
    const int tid = threadIdx.x;
    const int d = tid & 127;
    const int rowoff = tid >> 7;
    float sum = 0.f, sq = 0.f;
    for (int n = blockIdx.x * 2 + rowoff; n < N_NODES; n += gridDim.x * 2) {
        const float v = H[(size_t)n * D + d];
        sum += v; sq += v * v;
    }
    s1[tid] = sum; s2[tid] = sq;
    __syncthreads();
    if (tid < 128) {
        atomicAdd(&fsum[d], s1[tid] + s1[tid + 128]);
        atomicAdd(&fsq[d],  s2[tid] + s2[tid + 128]);
    }
}

__global__ void bn_apply(float* __restrict__ H, const float* __restrict__ fsum,
                         const float* __restrict__ fsq, const float* __restrict__ g,
                         const float* __restrict__ b)
{
    const int idx = blockIdx.x * blockDim.x + threadIdx.x;
    const int total = N_NODES * D / 4;
    if (idx >= total) return;
    float4 h = ((const float4*)H)[idx];
    float hv[4] = {h.x, h.y, h.z, h.w};
    const int dbase = (idx * 4) & 127;
    float o[4];
    #pragma unroll
    for (int c = 0; c < 4; ++c) {
        const int d = dbase + c;
        const float mu = fsum[d] * (1.0f / N_NODES);
        const float var = fsq[d] * (1.0f / N_NODES) - mu * mu;
        const float sc = g[d] * rsqrtf(var + EPS);
        o[c] = (hv[c] - mu) * sc + b[d];
    }
    ((float4*)H)[idx] = make_float4(o[0], o[1], o[2], o[3]);
}

// ---------------- Pooling ----------------
// batch is sorted: graph boundaries via binary search, no atomics.
__global__ void find_gstart(const int* __restrict__ batch, int* __restrict__ gstart) {
    const int g = threadIdx.x;
    if (g > N_GRAPHS) return;
    int lo = 0, hi = N_NODES;
    while (lo < hi) {
        int mid = (lo + hi) >> 1;
        if (batch[mid] < g) lo = mid + 1; else hi = mid;
    }
    gstart[g] = lo;   // first index with batch[i] >= g
}

// phase 1: 64*PCHUNK blocks, each does a strided slice of one graph
__global__ void pool_partial(const float* __restrict__ X, const int* __restrict__ gstart,
                             float* __restrict__ psum, float* __restrict__ pmax)
{
    const int g = blockIdx.x / PCHUNK;
    const int c = blockIdx.x % PCHUNK;
    const int d = threadIdx.x;     // 128
    const int lo = gstart[g], hi = gstart[g + 1];
    float sum = 0.f, mx = -INFINITY;
    for (int n = lo + c; n < hi; n += PCHUNK) {
        const float v = X[(size_t)n * D + d];
        sum += v;
        mx = fmaxf(mx, v);
    }
    psum[(size_t)blockIdx.x * D + d] = sum;
    pmax[(size_t)blockIdx.x * D + d] = mx;
}

// phase 2: 64 blocks combine PCHUNK partials
__global__ void pool_combine(const float* __restrict__ psum, const float* __restrict__ pmax,
                             const int* __restrict__ gstart,
                             float* __restrict__ gap, float* __restrict__ gsp)
{
    const int g = blockIdx.x;      // 64
    const int d = threadIdx.x;     // 128
    float sum = 0.f, mx = -INFINITY;
    #pragma unroll
    for (int c = 0; c < PCHUNK; ++c) {
        sum += psum[(size_t)(g * PCHUNK + c) * D + d];
        mx = fmaxf(mx, pmax[(size_t)(g * PCHUNK + c) * D + d]);
    }
    const int cnt = gstart[g + 1] - gstart[g];
    gap[g * D + d] = sum / fmaxf((float)cnt, 1.0f);
    gsp[g * D + d] = (cnt > 0) ? mx : 0.0f;
}

// ---------------- BN over rows (small) ----------------
__global__ void bn_rows(const float* __restrict__ A, int rows, int cols,
                        const float* __restrict__ g, const float* __restrict__ b,
                        float* __restrict__ out, int out_cols, int out_off)
{
    const int c = blockIdx.x * blockDim.x + threadIdx.x;
    if (c >= cols) return;
    float sum = 0.f, sq = 0.f;
    for (int r = 0; r < rows; ++r) {
        const float v = A[r * cols + c];
        sum += v; sq += v * v;
    }
    const float mu = sum / rows;
    const float var = sq / rows - mu * mu;
    const float sc = g[c] * rsqrtf(var + EPS);
    const float sh = b[c] - mu * sc;
    for (int r = 0; r < rows; ++r) {
        out[r * out_cols + out_off + c] = A[r * cols + c] * sc + sh;
    }
}

// ---------------- small GEMM: out = [relu](A @ W + bias) ----------------
// grid = rows, block = 256 (>= C, >= staging for K<=256)
__global__ void gemm_small(const float* __restrict__ A, const float* __restrict__ W,
                           const float* __restrict__ bias, float* __restrict__ out,
                           int K, int C, int relu)
{
    __shared__ float as[256];
    const int r = blockIdx.x;
    for (int k = threadIdx.x; k < K; k += blockDim.x) as[k] = A[r * K + k];
    __syncthreads();
    const int j = threadIdx.x;
    if (j < C) {
        float acc = bias[j];
        for (int k = 0; k < K; ++k) acc = fmaf(as[k], W[k * C + j], acc);
        if (relu) acc = fmaxf(acc, 0.f);
        out[r * C + j] = acc;
    }
}

extern "C" void kernel_launch(void* const* d_in, const int* in_sizes, int n_in,
                              void* d_out, int out_size, void* d_ws, size_t ws_size,
                              hipStream_t stream)
{
    const float* x     = (const float*)d_in[0];
    const int*   ei    = (const int*)d_in[1];
    const int*   srcE  = ei;                // edge_index[0]
    const int*   dstE  = ei + N_EDGES;      // edge_index[1]
    const int*   batch = (const int*)d_in[2];
    const float* Wk = (const float*)d_in[3];  const float* bk = (const float*)d_in[4];
    const float* Wq = (const float*)d_in[5];  const float* bq = (const float*)d_in[6];
    const float* Wv = (const float*)d_in[7];  const float* bv = (const float*)d_in[8];
    const float* Ws = (const float*)d_in[9];  const float* bs = (const float*)d_in[10];
    const float* g_cl = (const float*)d_in[11]; const float* b_cl = (const float*)d_in[12];
    const float* g_gap = (const float*)d_in[13]; const float* b_gap = (const float*)d_in[14];
    const float* g_gsp = (const float*)d_in[15]; const float* b_gsp = (const float*)d_in[16];
    const float* W1 = (const float*)d_in[17]; const float* b1 = (const float*)d_in[18];
    const float* g1 = (const float*)d_in[19]; const float* bt1 = (const float*)d_in[20];
    const float* W2 = (const float*)d_in[21]; const float* b2 = (const float*)d_in[22];
    const float* g2 = (const float*)d_in[23]; const float* bt2 = (const float*)d_in[24];
    const float* Wl = (const float*)d_in[25]; const float* bl = (const float*)d_in[26];
    float* out = (float*)d_out;

    // ---- workspace carve ----
    char* ws = (char*)d_ws;
    size_t off = 0;
    const size_t bufB = (size_t)N_NODES * D * sizeof(float);   // 25.6 MB
    float* Kb = (float*)(ws + off); off = align256(off + bufB);
    float* Qb = (float*)(ws + off); off = align256(off + bufB);
    float* Vb = (float*)(ws + off); off = align256(off + bufB);
    float* Sb = (float*)(ws + off); off = align256(off + bufB);
    float* H  = (float*)(ws + off); off = align256(off + bufB);   // persistent node features
    float* fsum = (float*)(ws + off); off = align256(off + 128 * sizeof(float));
    float* fsq  = (float*)(ws + off); off = align256(off + 128 * sizeof(float));
    int* cnt       = (int*)(ws + off); off = align256(off + (size_t)N_NODES * sizeof(int));
    int* row_start = (int*)(ws + off); off = align256(off + (size_t)(N_NODES + 1) * sizeof(int));
    int* cursor    = (int*)(ws + off); off = align256(off + (size_t)(N_NODES + 1) * sizeof(int));
    int* colI      = (int*)(ws + off); off = align256(off + (size_t)N_EDGES * sizeof(int));
    int* gstart    = (int*)(ws + off); off = align256(off + (N_GRAPHS + 1) * sizeof(int));
    float* psum = (float*)(ws + off); off = align256(off + (size_t)N_GRAPHS * PCHUNK * D * sizeof(float));
    float* pmax = (float*)(ws + off); off = align256(off + (size_t)N_GRAPHS * PCHUNK * D * sizeof(float));
    float* gap = (float*)(ws + off); off = align256(off + (size_t)N_GRAPHS * D * sizeof(float));
    float* gsp = (float*)(ws + off); off = align256(off + (size_t)N_GRAPHS * D * sizeof(float));
    float* h0  = (float*)(ws + off); off = align256(off + (size_t)N_GRAPHS * 256 * sizeof(float));
    float* h1  = (float*)(ws + off); off = align256(off + (size_t)N_GRAPHS * 256 * sizeof(float));
    float* h2  = (float*)(ws + off); off = align256(off + (size_t)N_GRAPHS * 128 * sizeof(float));
    if (off > ws_size) return;  // insufficient workspace -> will fail validation visibly

    // ---- CSR build (once; reused across the 3 layers) ----
    hipMemsetAsync(cnt, 0, (size_t)N_NODES * sizeof(int), stream);
    hist_dst<<<(N_EDGES + 255) / 256, 256, 0, stream>>>(dstE, cnt);
    scan_rows<<<1, 1024, 0, stream>>>(cnt, row_start, cursor);
    fill_csr<<<(N_EDGES + 255) / 256, 256, 0, stream>>>(srcE, dstE, cursor, colI);
    find_gstart<<<1, 128, 0, stream>>>(batch, gstart);

    // ---- 3 conv layers ----
    for (int i = 0; i < 3; ++i) {
        const float* Xin = (i == 0) ? x : H;
        gemm_kqvs<<<N_NODES / 16, 256, 0, stream>>>(
            Xin,
            Wk + (size_t)i * D * D, bk + i * D,
            Wq + (size_t)i * D * D, bq + i * D,
            Wv + (size_t)i * D * D, bv + i * D,
            Ws + (size_t)i * D * D, bs + i * D,
            Kb, Qb, Vb, Sb);
        aggregate<<<N_NODES / 2, 256, 0, stream>>>(Kb, Qb, Vb, Sb, row_start, colI, H);
        hipMemsetAsync(fsum, 0, 128 * sizeof(float), stream);
        hipMemsetAsync(fsq, 0, 128 * sizeof(float), stream);
        bn_stats<<<256, 256, 0, stream>>>(H, fsum, fsq);
        bn_apply<<<(N_NODES * D / 4 + 255) / 256, 256, 0, stream>>>(
            H, fsum, fsq, g_cl + i * D, b_cl + i * D);
    }

    // ---- pooling ----
    pool_partial<<<N_GRAPHS * PCHUNK, 128, 0, stream>>>(H, gstart, psum, pmax);
    pool_combine<<<N_GRAPHS, 128, 0, stream>>>(psum, pmax, gstart, gap, gsp);
    bn_rows<<<1, 128, 0, stream>>>(gap, N_GRAPHS, 128, g_gap, b_gap, h0, 256, 0);
    bn_rows<<<1, 128, 0, stream>>>(gsp, N_GRAPHS, 128, g_gsp, b_gsp, h0, 256, 128);

    // ---- MLP head ----
    gemm_small<<<N_GRAPHS, 256, 0, stream>>>(h0, W1, b1, h1, 256, 256, 1);
    bn_rows<<<1, 256, 0, stream>>>(h1, N_GRAPHS, 256, g1, bt1, h1, 256, 0);
    gemm_small<<<N_GRAPHS, 256, 0, stream>>>(h1, W2, b2, h2, 256, 128, 1);
    bn_rows<<<1, 128, 0, stream>>>(h2, N_GRAPHS, 128, g2, bt2, h2, 128, 0);
    gemm_small<<<N_GRAPHS, 256, 0, stream>>>(h2, Wl, bl, out, 128, 5, 0);
}

// Round 5
// 1418.772 us; speedup vs baseline: 1.0773x; 1.0773x over previous
//
#include <hip/hip_runtime.h>
#include <math.h>

#define N_NODES 50000
#define N_PAD 50048            // padded rows for MFMA tiles (multiple of 16)
#define N_EDGES 800000
#define D 128
#define N_GRAPHS 64
#define EPS 1e-5f
#define PCHUNK 16

typedef __attribute__((ext_vector_type(8))) short bf16x8;
typedef __attribute__((ext_vector_type(4))) float f32x4;

static inline size_t align256(size_t x) { return (x + 255) & ~(size_t)255; }

// ---------- bf16 split helpers (fp32 = hi + lo, each bf16) ----------
__device__ inline unsigned short f2bf(float x) {
    unsigned u = __builtin_bit_cast(unsigned, x);
    u += 0x7FFFu + ((u >> 16) & 1u);      // RNE
    return (unsigned short)(u >> 16);
}
__device__ inline float bf2f(unsigned short h) {
    unsigned u = (unsigned)h << 16;
    return __builtin_bit_cast(float, u);
}

// ---------- weight prep: split + transpose ----------
// Wsrc: [3][128][128] (k-major). Out: [3*4 mats][j=128][k=128] hi/lo bf16.
// grid: 3*4*128 blocks (layer,mat,j), 128 threads (k).
__global__ void prep_w(const float* __restrict__ Wk, const float* __restrict__ Wq,
                       const float* __restrict__ Wv, const float* __restrict__ Ws,
                       unsigned short* __restrict__ Whi, unsigned short* __restrict__ Wlo)
{
    const int j = blockIdx.x & 127;
    const int mat = (blockIdx.x >> 7) & 3;
    const int layer = blockIdx.x >> 9;
    const int k = threadIdx.x;
    const float* Wsrc = (mat == 0) ? Wk : (mat == 1) ? Wq : (mat == 2) ? Wv : Ws;
    const float w = Wsrc[((size_t)layer * D + k) * D + j];
    const unsigned short hi = f2bf(w);
    const unsigned short lo = f2bf(w - bf2f(hi));
    const size_t o = (((size_t)layer * 4 + mat) * D + j) * D + k;
    Whi[o] = hi;
    Wlo[o] = lo;
}

// ---------- split: f32 [N_NODES][128] -> hi/lo bf16 [N_PAD][128] (pad rows = 0) ----------
__global__ void convert_split(const float* __restrict__ X,
                              unsigned short* __restrict__ Xhi, unsigned short* __restrict__ Xlo)
{
    const size_t idx = (size_t)blockIdx.x * blockDim.x + threadIdx.x;  // one per 4 elems
    if (idx >= (size_t)N_PAD * (D / 4)) return;
    const size_t n = idx >> 5;
    float4 v = make_float4(0.f, 0.f, 0.f, 0.f);
    if (n < N_NODES) v = ((const float4*)X)[idx];
    float xv[4] = {v.x, v.y, v.z, v.w};
    unsigned short hi[4], lo[4];
    #pragma unroll
    for (int c = 0; c < 4; ++c) {
        hi[c] = f2bf(xv[c]);
        lo[c] = f2bf(xv[c] - bf2f(hi[c]));
    }
    ((ushort4*)Xhi)[idx] = make_ushort4(hi[0], hi[1], hi[2], hi[3]);
    ((ushort4*)Xlo)[idx] = make_ushort4(lo[0], lo[1], lo[2], lo[3]);
}

// ---------- MFMA GEMM: K,Q,V,S = X @ [Wk|Wq|Wv|Ws] + b (split-bf16 fp32 emu) ----------
// grid: N_PAD/16 blocks, 256 threads (4 waves). Wave w computes matrix w
// (0:K 1:Q 2:V 3:S) for a 16-row stripe, all 128 cols (8 MFMA tiles).
__global__ void gemm_kqvs_mfma(
    const unsigned short* __restrict__ Xhi, const unsigned short* __restrict__ Xlo,
    const unsigned short* __restrict__ Whi, const unsigned short* __restrict__ Wlo, // [4][128][128] (this layer)
    const float* __restrict__ bk, const float* __restrict__ bq,
    const float* __restrict__ bv, const float* __restrict__ bs,
    float* __restrict__ Kb, float* __restrict__ Qb,
    float* __restrict__ Vb, float* __restrict__ Sb)
{
    const int tid = threadIdx.x;
    const int wave = tid >> 6;                 // matrix id 0..3
    const int lane = tid & 63;
    const int l16 = lane & 15;
    const int lhi = lane >> 4;                 // 0..3
    const int r0 = blockIdx.x * 16;

    // A fragments: rows r0+l16, k = c*32 + lhi*8 (+0..7)
    bf16x8 ah[4], al[4];
    const size_t arow = (size_t)(r0 + l16) * D;
    #pragma unroll
    for (int c = 0; c < 4; ++c) {
        ah[c] = *(const bf16x8*)(Xhi + arow + c * 32 + lhi * 8);
        al[c] = *(const bf16x8*)(Xlo + arow + c * 32 + lhi * 8);
    }

    f32x4 acc[8];
    #pragma unroll
    for (int t = 0; t < 8; ++t) acc[t] = (f32x4){0.f, 0.f, 0.f, 0.f};

    const unsigned short* wh = Whi + (size_t)wave * D * D;
    const unsigned short* wl = Wlo + (size_t)wave * D * D;
    #pragma unroll
    for (int t = 0; t < 8; ++t) {
        const size_t wb = (size_t)(t * 16 + l16) * D;
        #pragma unroll
        for (int c = 0; c < 4; ++c) {
            const bf16x8 bh = *(const bf16x8*)(wh + wb + c * 32 + lhi * 8);
            const bf16x8 bl = *(const bf16x8*)(wl + wb + c * 32 + lhi * 8);
            acc[t] = __builtin_amdgcn_mfma_f32_16x16x32_bf16(ah[c], bh, acc[t], 0, 0, 0);
            acc[t] = __builtin_amdgcn_mfma_f32_16x16x32_bf16(al[c], bh, acc[t], 0, 0, 0);
            acc[t] = __builtin_amdgcn_mfma_f32_16x16x32_bf16(ah[c], bl, acc[t], 0, 0, 0);
        }
    }

    float* ob = (wave == 0) ? Kb : (wave == 1) ? Qb : (wave == 2) ? Vb : Sb;
    const float* bb = (wave == 0) ? bk : (wave == 1) ? bq : (wave == 2) ? bv : bs;
    // C tile layout: col = l16, row = lhi*4 + reg (m89-verified)
    #pragma unroll
    for (int t = 0; t < 8; ++t) {
        const int lc = t * 16 + l16;
        const float bias = bb[lc];
        #pragma unroll
        for (int rgi = 0; rgi < 4; ++rgi) {
            const int row = r0 + lhi * 4 + rgi;
            if (row < N_NODES) ob[(size_t)row * D + lc] = acc[t][rgi] + bias;
        }
    }
}

// ---------------- CSR build ----------------
__global__ void hist_dst(const int* __restrict__ dst, int* __restrict__ cnt) {
    int e = blockIdx.x * blockDim.x + threadIdx.x;
    if (e < N_EDGES) atomicAdd(&cnt[dst[e]], 1);
}

__global__ void scan_rows(const int* __restrict__ cnt, int* __restrict__ row_start,
                          int* __restrict__ cursor) {
    __shared__ int partial[1024];
    const int T = 1024;
    const int t = threadIdx.x;
    const int chunk = (N_NODES + T - 1) / T;
    const int lo = t * chunk;
    const int hi = min(lo + chunk, N_NODES);
    int s = 0;
    for (int i = lo; i < hi; ++i) s += cnt[i];
    partial[t] = s;
    __syncthreads();
    for (int off = 1; off < T; off <<= 1) {
        int add = (t >= off) ? partial[t - off] : 0;
        __syncthreads();
        partial[t] += add;
        __syncthreads();
    }
    int base = (t == 0) ? 0 : partial[t - 1];
    for (int i = lo; i < hi; ++i) {
        row_start[i] = base;
        cursor[i] = base;
        base += cnt[i];
    }
    if (t == T - 1) { row_start[N_NODES] = partial[T - 1]; cursor[N_NODES] = partial[T - 1]; }
}

__global__ void fill_csr(const int* __restrict__ src, const int* __restrict__ dst,
                         int* __restrict__ cursor, int* __restrict__ col) {
    int e = blockIdx.x * blockDim.x + threadIdx.x;
    if (e < N_EDGES) {
        int d = dst[e];
        int p = atomicAdd(&cursor[d], 1);
        col[p] = src[e];
    }
}

// ---------------- Edge aggregation + skip + ReLU ----------------
__global__ void aggregate(const float* __restrict__ Kb, const float* __restrict__ Qb,
                          const float* __restrict__ Vb, const float* __restrict__ Sb,
                          const int* __restrict__ row_start, const int* __restrict__ col,
                          float* __restrict__ H)
{
    const int tid = threadIdx.x;
    const int node = blockIdx.x * 2 + (tid >> 7);
    const int d = tid & 127;
    const float kd = Kb[(size_t)node * D + d];
    float acc = 0.f;
    const int e0 = row_start[node];
    const int e1 = row_start[node + 1];
    for (int e = e0; e < e1; ++e) {
        const int s = col[e];
        const float qd = Qb[(size_t)s * D + d];
        const float vd = Vb[(size_t)s * D + d];
        const float z = kd + qd;
        const float gate = 1.0f / (1.0f + __expf(-z));
        acc = fmaf(gate, vd, acc);
    }
    H[(size_t)node * D + d] = fmaxf(acc + Sb[(size_t)node * D + d], 0.0f);
}

// ---------------- BatchNorm over nodes ----------------
__global__ void bn_stats(const float* __restrict__ H, float* __restrict__ fsum,
                         float* __restrict__ fsq)
{
    __shared__ float s1[256], s2[256];
    const int tid = threadIdx.x;
    const int d = tid & 127;
    const int rowoff = tid >> 7;
    float sum = 0.f, sq = 0.f;
    for (int n = blockIdx.x * 2 + rowoff; n < N_NODES; n += gridDim.x * 2) {
        const float v = H[(size_t)n * D + d];
        sum += v; sq += v * v;
    }
    s1[tid] = sum; s2[tid] = sq;
    __syncthreads();
    if (tid < 128) {
        atomicAdd(&fsum[d], s1[tid] + s1[tid + 128]);
        atomicAdd(&fsq[d],  s2[tid] + s2[tid + 128]);
    }
}

__global__ void bn_apply(float* __restrict__ H, const float* __restrict__ fsum,
                         const float* __restrict__ fsq, const float* __restrict__ g,
                         const float* __restrict__ b)
{
    const int idx = blockIdx.x * blockDim.x + threadIdx.x;
    const int total = N_NODES * D / 4;
    if (idx >= total) return;
    float4 h = ((const float4*)H)[idx];
    float hv[4] = {h.x, h.y, h.z, h.w};
    const int dbase = (idx * 4) & 127;
    float o[4];
    #pragma unroll
    for (int c = 0; c < 4; ++c) {
        const int d = dbase + c;
        const float mu = fsum[d] * (1.0f / N_NODES);
        const float var = fsq[d] * (1.0f / N_NODES) - mu * mu;
        const float sc = g[d] * rsqrtf(var + EPS);
        o[c] = (hv[c] - mu) * sc + b[d];
    }
    ((float4*)H)[idx] = make_float4(o[0], o[1], o[2], o[3]);
}

// ---------------- Pooling ----------------
__global__ void find_gstart(const int* __restrict__ batch, int* __restrict__ gstart) {
    const int g = threadIdx.x;
    if (g > N_GRAPHS) return;
    int lo = 0, hi = N_NODES;
    while (lo < hi) {
        int mid = (lo + hi) >> 1;
        if (batch[mid] < g) lo = mid + 1; else hi = mid;
    }
    gstart[g] = lo;
}

__global__ void pool_partial(const float* __restrict__ X, const int* __restrict__ gstart,
                             float* __restrict__ psum, float* __restrict__ pmax)
{
    const int g = blockIdx.x / PCHUNK;
    const int c = blockIdx.x % PCHUNK;
    const int d = threadIdx.x;
    const int lo = gstart[g], hi = gstart[g + 1];
    float sum = 0.f, mx = -INFINITY;
    for (int n = lo + c; n < hi; n += PCHUNK) {
        const float v = X[(size_t)n * D + d];
        sum += v;
        mx = fmaxf(mx, v);
    }
    psum[(size_t)blockIdx.x * D + d] = sum;
    pmax[(size_t)blockIdx.x * D + d] = mx;
}

__global__ void pool_combine(const float* __restrict__ psum, const float* __restrict__ pmax,
                             const int* __restrict__ gstart,
                             float* __restrict__ gap, float* __restrict__ gsp)
{
    const int g = blockIdx.x;
    const int d = threadIdx.x;
    float sum = 0.f, mx = -INFINITY;
    #pragma unroll
    for (int c = 0; c < PCHUNK; ++c) {
        sum += psum[(size_t)(g * PCHUNK + c) * D + d];
        mx = fmaxf(mx, pmax[(size_t)(g * PCHUNK + c) * D + d]);
    }
    const int cnt = gstart[g + 1] - gstart[g];
    gap[g * D + d] = sum / fmaxf((float)cnt, 1.0f);
    gsp[g * D + d] = (cnt > 0) ? mx : 0.0f;
}

// ---------------- BN over rows (small) ----------------
__global__ void bn_rows(const float* __restrict__ A, int rows, int cols,
                        const float* __restrict__ g, const float* __restrict__ b,
                        float* __restrict__ out, int out_cols, int out_off)
{
    const int c = blockIdx.x * blockDim.x + threadIdx.x;
    if (c >= cols) return;
    float sum = 0.f, sq = 0.f;
    for (int r = 0; r < rows; ++r) {
        const float v = A[r * cols + c];
        sum += v; sq += v * v;
    }
    const float mu = sum / rows;
    const float var = sq / rows - mu * mu;
    const float sc = g[c] * rsqrtf(var + EPS);
    const float sh = b[c] - mu * sc;
    for (int r = 0; r < rows; ++r) {
        out[r * out_cols + out_off + c] = A[r * cols + c] * sc + sh;
    }
}

// ---------------- small GEMM: out = [relu](A @ W + bias) ----------------
__global__ void gemm_small(const float* __restrict__ A, const float* __restrict__ W,
                           const float* __restrict__ bias, float* __restrict__ out,
                           int K, int C, int relu)
{
    __shared__ float as[256];
    const int r = blockIdx.x;
    for (int k = threadIdx.x; k < K; k += blockDim.x) as[k] = A[r * K + k];
    __syncthreads();
    const int j = threadIdx.x;
    if (j < C) {
        float acc = bias[j];
        for (int k = 0; k < K; ++k) acc = fmaf(as[k], W[k * C + j], acc);
        if (relu) acc = fmaxf(acc, 0.f);
        out[r * C + j] = acc;
    }
}

extern "C" void kernel_launch(void* const* d_in, const int* in_sizes, int n_in,
                              void* d_out, int out_size, void* d_ws, size_t ws_size,
                              hipStream_t stream)
{
    const float* x     = (const float*)d_in[0];
    const int*   ei    = (const int*)d_in[1];
    const int*   srcE  = ei;
    const int*   dstE  = ei + N_EDGES;
    const int*   batch = (const int*)d_in[2];
    const float* Wk = (const float*)d_in[3];  const float* bk = (const float*)d_in[4];
    const float* Wq = (const float*)d_in[5];  const float* bq = (const float*)d_in[6];
    const float* Wv = (const float*)d_in[7];  const float* bv = (const float*)d_in[8];
    const float* Ws = (const float*)d_in[9];  const float* bs = (const float*)d_in[10];
    const float* g_cl = (const float*)d_in[11]; const float* b_cl = (const float*)d_in[12];
    const float* g_gap = (const float*)d_in[13]; const float* b_gap = (const float*)d_in[14];
    const float* g_gsp = (const float*)d_in[15]; const float* b_gsp = (const float*)d_in[16];
    const float* W1 = (const float*)d_in[17]; const float* b1 = (const float*)d_in[18];
    const float* g1 = (const float*)d_in[19]; const float* bt1 = (const float*)d_in[20];
    const float* W2 = (const float*)d_in[21]; const float* b2 = (const float*)d_in[22];
    const float* g2 = (const float*)d_in[23]; const float* bt2 = (const float*)d_in[24];
    const float* Wl = (const float*)d_in[25]; const float* bl = (const float*)d_in[26];
    float* out = (float*)d_out;

    // ---- workspace carve ----
    char* ws = (char*)d_ws;
    size_t off = 0;
    const size_t bufB = (size_t)N_NODES * D * sizeof(float);   // 25.6 MB
    float* Kb = (float*)(ws + off); off = align256(off + bufB);
    float* Qb = (float*)(ws + off); off = align256(off + bufB);
    float* Vb = (float*)(ws + off); off = align256(off + bufB);
    float* Sb = (float*)(ws + off); off = align256(off + bufB);
    float* H  = (float*)(ws + off); off = align256(off + bufB);
    unsigned short* Xhi = (unsigned short*)(ws + off); off = align256(off + (size_t)N_PAD * D * 2);
    unsigned short* Xlo = (unsigned short*)(ws + off); off = align256(off + (size_t)N_PAD * D * 2);
    unsigned short* Whi = (unsigned short*)(ws + off); off = align256(off + (size_t)12 * D * D * 2);
    unsigned short* Wlo = (unsigned short*)(ws + off); off = align256(off + (size_t)12 * D * D * 2);
    float* fsum = (float*)(ws + off); off = align256(off + 128 * sizeof(float));
    float* fsq  = (float*)(ws + off); off = align256(off + 128 * sizeof(float));
    int* cnt       = (int*)(ws + off); off = align256(off + (size_t)N_NODES * sizeof(int));
    int* row_start = (int*)(ws + off); off = align256(off + (size_t)(N_NODES + 1) * sizeof(int));
    int* cursor    = (int*)(ws + off); off = align256(off + (size_t)(N_NODES + 1) * sizeof(int));
    int* colI      = (int*)(ws + off); off = align256(off + (size_t)N_EDGES * sizeof(int));
    int* gstart    = (int*)(ws + off); off = align256(off + (N_GRAPHS + 1) * sizeof(int));
    float* psum = (float*)(ws + off); off = align256(off + (size_t)N_GRAPHS * PCHUNK * D * sizeof(float));
    float* pmax = (float*)(ws + off); off = align256(off + (size_t)N_GRAPHS * PCHUNK * D * sizeof(float));
    float* gap = (float*)(ws + off); off = align256(off + (size_t)N_GRAPHS * D * sizeof(float));
    float* gsp = (float*)(ws + off); off = align256(off + (size_t)N_GRAPHS * D * sizeof(float));
    float* h0  = (float*)(ws + off); off = align256(off + (size_t)N_GRAPHS * 256 * sizeof(float));
    float* h1  = (float*)(ws + off); off = align256(off + (size_t)N_GRAPHS * 256 * sizeof(float));
    float* h2  = (float*)(ws + off); off = align256(off + (size_t)N_GRAPHS * 128 * sizeof(float));
    if (off > ws_size) return;

    // ---- one-time prep ----
    hipMemsetAsync(cnt, 0, (size_t)N_NODES * sizeof(int), stream);
    hist_dst<<<(N_EDGES + 255) / 256, 256, 0, stream>>>(dstE, cnt);
    scan_rows<<<1, 1024, 0, stream>>>(cnt, row_start, cursor);
    fill_csr<<<(N_EDGES + 255) / 256, 256, 0, stream>>>(srcE, dstE, cursor, colI);
    find_gstart<<<1, 128, 0, stream>>>(batch, gstart);
    prep_w<<<12 * 128, 128, 0, stream>>>(Wk, Wq, Wv, Ws, Whi, Wlo);
    convert_split<<<(N_PAD * (D / 4) + 255) / 256, 256, 0, stream>>>(x, Xhi, Xlo);

    // ---- 3 conv layers ----
    for (int i = 0; i < 3; ++i) {
        gemm_kqvs_mfma<<<N_PAD / 16, 256, 0, stream>>>(
            Xhi, Xlo,
            Whi + (size_t)i * 4 * D * D, Wlo + (size_t)i * 4 * D * D,
            bk + i * D, bq + i * D, bv + i * D, bs + i * D,
            Kb, Qb, Vb, Sb);
        aggregate<<<N_NODES / 2, 256, 0, stream>>>(Kb, Qb, Vb, Sb, row_start, colI, H);
        hipMemsetAsync(fsum, 0, 128 * sizeof(float), stream);
        hipMemsetAsync(fsq, 0, 128 * sizeof(float), stream);
        bn_stats<<<256, 256, 0, stream>>>(H, fsum, fsq);
        bn_apply<<<(N_NODES * D / 4 + 255) / 256, 256, 0, stream>>>(
            H, fsum, fsq, g_cl + i * D, b_cl + i * D);
        if (i < 2) {
            convert_split<<<(N_PAD * (D / 4) + 255) / 256, 256, 0, stream>>>(H, Xhi, Xlo);
        }
    }

    // ---- pooling ----
    pool_partial<<<N_GRAPHS * PCHUNK, 128, 0, stream>>>(H, gstart, psum, pmax);
    pool_combine<<<N_GRAPHS, 128, 0, stream>>>(psum, pmax, gstart, gap, gsp);
    bn_rows<<<1, 128, 0, stream>>>(gap, N_GRAPHS, 128, g_gap, b_gap, h0, 256, 0);
    bn_rows<<<1, 128, 0, stream>>>(gsp, N_GRAPHS, 128, g_gsp, b_gsp, h0, 256, 128);

    // ---- MLP head ----
    gemm_small<<<N_GRAPHS, 256, 0, stream>>>(h0, W1, b1, h1, 256, 256, 1);
    bn_rows<<<1, 256, 0, stream>>>(h1, N_GRAPHS, 256, g1, bt1, h1, 256, 0);
    gemm_small<<<N_GRAPHS, 256, 0, stream>>>(h1, W2, b2, h2, 256, 128, 1);
    bn_rows<<<1, 128, 0, stream>>>(h2, N_GRAPHS, 128, g2, bt2, h2, 128, 0);
    gemm_small<<<N_GRAPHS, 256, 0, stream>>>(h2, Wl, bl, out, 128, 5, 0);
}

// Round 6
// 1235.777 us; speedup vs baseline: 1.2369x; 1.1481x over previous
//
#include <hip/hip_runtime.h>
#include <math.h>

#define N_NODES 50000
#define N_PAD 50048            // padded rows for MFMA tiles (multiple of 16)
#define N_EDGES 800000
#define D 128
#define N_GRAPHS 64
#define EPS 1e-5f
#define PCHUNK 16

typedef __attribute__((ext_vector_type(8))) short bf16x8;
typedef __attribute__((ext_vector_type(4))) float f32x4;

static inline size_t align256(size_t x) { return (x + 255) & ~(size_t)255; }

// ---------- bf16 split helpers (fp32 = hi + lo, each bf16) ----------
__device__ inline unsigned short f2bf(float x) {
    unsigned u = __builtin_bit_cast(unsigned, x);
    u += 0x7FFFu + ((u >> 16) & 1u);      // RNE
    return (unsigned short)(u >> 16);
}
__device__ inline float bf2f(unsigned short h) {
    unsigned u = (unsigned)h << 16;
    return __builtin_bit_cast(float, u);
}

// fast sigmoid: 1/(1+e^-z) with raw v_rcp (sig precision irrelevant at 1ulp)
__device__ inline float fsigmoid(float z) {
    return __builtin_amdgcn_rcpf(1.0f + __expf(-z));
}

// ---------- weight prep: split + transpose ----------
__global__ void prep_w(const float* __restrict__ Wk, const float* __restrict__ Wq,
                       const float* __restrict__ Wv, const float* __restrict__ Ws,
                       unsigned short* __restrict__ Whi, unsigned short* __restrict__ Wlo)
{
    const int j = blockIdx.x & 127;
    const int mat = (blockIdx.x >> 7) & 3;
    const int layer = blockIdx.x >> 9;
    const int k = threadIdx.x;
    const float* Wsrc = (mat == 0) ? Wk : (mat == 1) ? Wq : (mat == 2) ? Wv : Ws;
    const float w = Wsrc[((size_t)layer * D + k) * D + j];
    const unsigned short hi = f2bf(w);
    const unsigned short lo = f2bf(w - bf2f(hi));
    const size_t o = (((size_t)layer * 4 + mat) * D + j) * D + k;
    Whi[o] = hi;
    Wlo[o] = lo;
}

// ---------- split: f32 [N_NODES][128] -> hi/lo bf16 [N_PAD][128] (pad rows = 0) ----------
__global__ void convert_split(const float* __restrict__ X,
                              unsigned short* __restrict__ Xhi, unsigned short* __restrict__ Xlo)
{
    const size_t idx = (size_t)blockIdx.x * blockDim.x + threadIdx.x;  // one per 4 elems
    if (idx >= (size_t)N_PAD * (D / 4)) return;
    const size_t n = idx >> 5;
    float4 v = make_float4(0.f, 0.f, 0.f, 0.f);
    if (n < N_NODES) v = ((const float4*)X)[idx];
    float xv[4] = {v.x, v.y, v.z, v.w};
    unsigned short hi[4], lo[4];
    #pragma unroll
    for (int c = 0; c < 4; ++c) {
        hi[c] = f2bf(xv[c]);
        lo[c] = f2bf(xv[c] - bf2f(hi[c]));
    }
    ((ushort4*)Xhi)[idx] = make_ushort4(hi[0], hi[1], hi[2], hi[3]);
    ((ushort4*)Xlo)[idx] = make_ushort4(lo[0], lo[1], lo[2], lo[3]);
}

// ---------- MFMA GEMM: K,Q,V,S = X @ [Wk|Wq|Wv|Ws] + b (split-bf16 fp32 emu) ----------
// grid: N_PAD/16 blocks, 256 threads (4 waves). Wave w computes matrix w
// (0:K 1:Q 2:V 3:S) for a 16-row stripe. Q,V go interleaved into QV (float2).
__global__ void gemm_kqvs_mfma(
    const unsigned short* __restrict__ Xhi, const unsigned short* __restrict__ Xlo,
    const unsigned short* __restrict__ Whi, const unsigned short* __restrict__ Wlo,
    const float* __restrict__ bk, const float* __restrict__ bq,
    const float* __restrict__ bv, const float* __restrict__ bs,
    float* __restrict__ Kb, float* __restrict__ QV, float* __restrict__ Sb)
{
    const int tid = threadIdx.x;
    const int wave = tid >> 6;                 // matrix id 0..3
    const int lane = tid & 63;
    const int l16 = lane & 15;
    const int lhi = lane >> 4;                 // 0..3
    const int r0 = blockIdx.x * 16;

    // A fragments: rows r0+l16, k = c*32 + lhi*8 (+0..7)
    bf16x8 ah[4], al[4];
    const size_t arow = (size_t)(r0 + l16) * D;
    #pragma unroll
    for (int c = 0; c < 4; ++c) {
        ah[c] = *(const bf16x8*)(Xhi + arow + c * 32 + lhi * 8);
        al[c] = *(const bf16x8*)(Xlo + arow + c * 32 + lhi * 8);
    }

    f32x4 acc[8];
    #pragma unroll
    for (int t = 0; t < 8; ++t) acc[t] = (f32x4){0.f, 0.f, 0.f, 0.f};

    const unsigned short* wh = Whi + (size_t)wave * D * D;
    const unsigned short* wl = Wlo + (size_t)wave * D * D;
    #pragma unroll
    for (int t = 0; t < 8; ++t) {
        const size_t wb = (size_t)(t * 16 + l16) * D;
        #pragma unroll
        for (int c = 0; c < 4; ++c) {
            const bf16x8 bh = *(const bf16x8*)(wh + wb + c * 32 + lhi * 8);
            const bf16x8 bl = *(const bf16x8*)(wl + wb + c * 32 + lhi * 8);
            acc[t] = __builtin_amdgcn_mfma_f32_16x16x32_bf16(ah[c], bh, acc[t], 0, 0, 0);
            acc[t] = __builtin_amdgcn_mfma_f32_16x16x32_bf16(al[c], bh, acc[t], 0, 0, 0);
            acc[t] = __builtin_amdgcn_mfma_f32_16x16x32_bf16(ah[c], bl, acc[t], 0, 0, 0);
        }
    }

    // C tile layout: col = l16, row = lhi*4 + reg (m89-verified)
    if (wave == 0 || wave == 3) {
        float* ob = (wave == 0) ? Kb : Sb;
        const float* bb = (wave == 0) ? bk : bs;
        #pragma unroll
        for (int t = 0; t < 8; ++t) {
            const int lc = t * 16 + l16;
            const float bias = bb[lc];
            #pragma unroll
            for (int rgi = 0; rgi < 4; ++rgi) {
                const int row = r0 + lhi * 4 + rgi;
                if (row < N_NODES) ob[(size_t)row * D + lc] = acc[t][rgi] + bias;
            }
        }
    } else {
        const float* bb = (wave == 1) ? bq : bv;
        float* base = QV + ((wave == 2) ? 1 : 0);   // .x = Q, .y = V
        #pragma unroll
        for (int t = 0; t < 8; ++t) {
            const int lc = t * 16 + l16;
            const float bias = bb[lc];
            #pragma unroll
            for (int rgi = 0; rgi < 4; ++rgi) {
                const int row = r0 + lhi * 4 + rgi;
                if (row < N_NODES) base[2 * ((size_t)row * D + lc)] = acc[t][rgi] + bias;
            }
        }
    }
}

// ---------------- CSR build ----------------
__global__ void hist_dst(const int* __restrict__ dst, int* __restrict__ cnt) {
    int e = blockIdx.x * blockDim.x + threadIdx.x;
    if (e < N_EDGES) atomicAdd(&cnt[dst[e]], 1);
}

__global__ void scan_rows(const int* __restrict__ cnt, int* __restrict__ row_start,
                          int* __restrict__ cursor) {
    __shared__ int partial[1024];
    const int T = 1024;
    const int t = threadIdx.x;
    const int chunk = (N_NODES + T - 1) / T;
    const int lo = t * chunk;
    const int hi = min(lo + chunk, N_NODES);
    int s = 0;
    for (int i = lo; i < hi; ++i) s += cnt[i];
    partial[t] = s;
    __syncthreads();
    for (int off = 1; off < T; off <<= 1) {
        int add = (t >= off) ? partial[t - off] : 0;
        __syncthreads();
        partial[t] += add;
        __syncthreads();
    }
    int base = (t == 0) ? 0 : partial[t - 1];
    for (int i = lo; i < hi; ++i) {
        row_start[i] = base;
        cursor[i] = base;
        base += cnt[i];
    }
    if (t == T - 1) { row_start[N_NODES] = partial[T - 1]; cursor[N_NODES] = partial[T - 1]; }
}

__global__ void fill_csr(const int* __restrict__ src, const int* __restrict__ dst,
                         int* __restrict__ cursor, int* __restrict__ col) {
    int e = blockIdx.x * blockDim.x + threadIdx.x;
    if (e < N_EDGES) {
        int d = dst[e];
        int p = atomicAdd(&cursor[d], 1);
        col[p] = src[e];
    }
}

// ---------------- Edge aggregation + skip + ReLU ----------------
// block 256 threads = 2 dst nodes (node uniform per wave-pair); 4-deep unroll
// keeps >=4 packed QV gathers in flight per wave.
__global__ void aggregate(const float* __restrict__ Kb, const float2* __restrict__ QV,
                          const float* __restrict__ Sb,
                          const int* __restrict__ row_start, const int* __restrict__ col,
                          float* __restrict__ H)
{
    const int tid = threadIdx.x;
    const int node = blockIdx.x * 2 + (tid >> 7);
    const int d = tid & 127;
    const float kd = Kb[(size_t)node * D + d];
    float acc = 0.f;
    const int e0 = row_start[node];
    const int e1 = row_start[node + 1];
    int e = e0;
    for (; e + 4 <= e1; e += 4) {
        const int s0 = col[e + 0];
        const int s1 = col[e + 1];
        const int s2 = col[e + 2];
        const int s3 = col[e + 3];
        const float2 a0 = QV[(size_t)s0 * D + d];
        const float2 a1 = QV[(size_t)s1 * D + d];
        const float2 a2 = QV[(size_t)s2 * D + d];
        const float2 a3 = QV[(size_t)s3 * D + d];
        acc = fmaf(fsigmoid(kd + a0.x), a0.y, acc);
        acc = fmaf(fsigmoid(kd + a1.x), a1.y, acc);
        acc = fmaf(fsigmoid(kd + a2.x), a2.y, acc);
        acc = fmaf(fsigmoid(kd + a3.x), a3.y, acc);
    }
    for (; e < e1; ++e) {
        const int s = col[e];
        const float2 a = QV[(size_t)s * D + d];
        acc = fmaf(fsigmoid(kd + a.x), a.y, acc);
    }
    H[(size_t)node * D + d] = fmaxf(acc + Sb[(size_t)node * D + d], 0.0f);
}

// ---------------- BatchNorm over nodes ----------------
__global__ void bn_stats(const float* __restrict__ H, float* __restrict__ fsum,
                         float* __restrict__ fsq)
{
    __shared__ float s1[256], s2[256];
    const int tid = threadIdx.x;
    const int d = tid & 127;
    const int rowoff = tid >> 7;
    float sum = 0.f, sq = 0.f;
    for (int n = blockIdx.x * 2 + rowoff; n < N_NODES; n += gridDim.x * 2) {
        const float v = H[(size_t)n * D + d];
        sum += v; sq += v * v;
    }
    s1[tid] = sum; s2[tid] = sq;
    __syncthreads();
    if (tid < 128) {
        atomicAdd(&fsum[d], s1[tid] + s1[tid + 128]);
        atomicAdd(&fsq[d],  s2[tid] + s2[tid + 128]);
    }
}

__global__ void bn_apply(float* __restrict__ H, const float* __restrict__ fsum,
                         const float* __restrict__ fsq, const float* __restrict__ g,
                         const float* __restrict__ b)
{
    const int idx = blockIdx.x * blockDim.x + threadIdx.x;
    const int total = N_NODES * D / 4;
    if (idx >= total) return;
    float4 h = ((const float4*)H)[idx];
    float hv[4] = {h.x, h.y, h.z, h.w};
    const int dbase = (idx * 4) & 127;
    float o[4];
    #pragma unroll
    for (int c = 0; c < 4; ++c) {
        const int d = dbase + c;
        const float mu = fsum[d] * (1.0f / N_NODES);
        const float var = fsq[d] * (1.0f / N_NODES) - mu * mu;
        const float sc = g[d] * rsqrtf(var + EPS);
        o[c] = (hv[c] - mu) * sc + b[d];
    }
    ((float4*)H)[idx] = make_float4(o[0], o[1], o[2], o[3]);
}

// ---------------- Pooling ----------------
__global__ void find_gstart(const int* __restrict__ batch, int* __restrict__ gstart) {
    const int g = threadIdx.x;
    if (g > N_GRAPHS) return;
    int lo = 0, hi = N_NODES;
    while (lo < hi) {
        int mid = (lo + hi) >> 1;
        if (batch[mid] < g) lo = mid + 1; else hi = mid;
    }
    gstart[g] = lo;
}

__global__ void pool_partial(const float* __restrict__ X, const int* __restrict__ gstart,
                             float* __restrict__ psum, float* __restrict__ pmax)
{
    const int g = blockIdx.x / PCHUNK;
    const int c = blockIdx.x % PCHUNK;
    const int d = threadIdx.x;
    const int lo = gstart[g], hi = gstart[g + 1];
    float sum = 0.f, mx = -INFINITY;
    for (int n = lo + c; n < hi; n += PCHUNK) {
        const float v = X[(size_t)n * D + d];
        sum += v;
        mx = fmaxf(mx, v);
    }
    psum[(size_t)blockIdx.x * D + d] = sum;
    pmax[(size_t)blockIdx.x * D + d] = mx;
}

__global__ void pool_combine(const float* __restrict__ psum, const float* __restrict__ pmax,
                             const int* __restrict__ gstart,
                             float* __restrict__ gap, float* __restrict__ gsp)
{
    const int g = blockIdx.x;
    const int d = threadIdx.x;
    float sum = 0.f, mx = -INFINITY;
    #pragma unroll
    for (int c = 0; c < PCHUNK; ++c) {
        sum += psum[(size_t)(g * PCHUNK + c) * D + d];
        mx = fmaxf(mx, pmax[(size_t)(g * PCHUNK + c) * D + d]);
    }
    const int cnt = gstart[g + 1] - gstart[g];
    gap[g * D + d] = sum / fmaxf((float)cnt, 1.0f);
    gsp[g * D + d] = (cnt > 0) ? mx : 0.0f;
}

// ---------------- BN over rows (small) ----------------
__global__ void bn_rows(const float* __restrict__ A, int rows, int cols,
                        const float* __restrict__ g, const float* __restrict__ b,
                        float* __restrict__ out, int out_cols, int out_off)
{
    const int c = blockIdx.x * blockDim.x + threadIdx.x;
    if (c >= cols) return;
    float sum = 0.f, sq = 0.f;
    for (int r = 0; r < rows; ++r) {
        const float v = A[r * cols + c];
        sum += v; sq += v * v;
    }
    const float mu = sum / rows;
    const float var = sq / rows - mu * mu;
    const float sc = g[c] * rsqrtf(var + EPS);
    const float sh = b[c] - mu * sc;
    for (int r = 0; r < rows; ++r) {
        out[r * out_cols + out_off + c] = A[r * cols + c] * sc + sh;
    }
}

// ---------------- small GEMM: out = [relu](A @ W + bias) ----------------
__global__ void gemm_small(const float* __restrict__ A, const float* __restrict__ W,
                           const float* __restrict__ bias, float* __restrict__ out,
                           int K, int C, int relu)
{
    __shared__ float as[256];
    const int r = blockIdx.x;
    for (int k = threadIdx.x; k < K; k += blockDim.x) as[k] = A[r * K + k];
    __syncthreads();
    const int j = threadIdx.x;
    if (j < C) {
        float acc = bias[j];
        for (int k = 0; k < K; ++k) acc = fmaf(as[k], W[k * C + j], acc);
        if (relu) acc = fmaxf(acc, 0.f);
        out[r * C + j] = acc;
    }
}

extern "C" void kernel_launch(void* const* d_in, const int* in_sizes, int n_in,
                              void* d_out, int out_size, void* d_ws, size_t ws_size,
                              hipStream_t stream)
{
    const float* x     = (const float*)d_in[0];
    const int*   ei    = (const int*)d_in[1];
    const int*   srcE  = ei;
    const int*   dstE  = ei + N_EDGES;
    const int*   batch = (const int*)d_in[2];
    const float* Wk = (const float*)d_in[3];  const float* bk = (const float*)d_in[4];
    const float* Wq = (const float*)d_in[5];  const float* bq = (const float*)d_in[6];
    const float* Wv = (const float*)d_in[7];  const float* bv = (const float*)d_in[8];
    const float* Ws = (const float*)d_in[9];  const float* bs = (const float*)d_in[10];
    const float* g_cl = (const float*)d_in[11]; const float* b_cl = (const float*)d_in[12];
    const float* g_gap = (const float*)d_in[13]; const float* b_gap = (const float*)d_in[14];
    const float* g_gsp = (const float*)d_in[15]; const float* b_gsp = (const float*)d_in[16];
    const float* W1 = (const float*)d_in[17]; const float* b1 = (const float*)d_in[18];
    const float* g1 = (const float*)d_in[19]; const float* bt1 = (const float*)d_in[20];
    const float* W2 = (const float*)d_in[21]; const float* b2 = (const float*)d_in[22];
    const float* g2 = (const float*)d_in[23]; const float* bt2 = (const float*)d_in[24];
    const float* Wl = (const float*)d_in[25]; const float* bl = (const float*)d_in[26];
    float* out = (float*)d_out;

    // ---- workspace carve ----
    char* ws = (char*)d_ws;
    size_t off = 0;
    const size_t bufB = (size_t)N_NODES * D * sizeof(float);   // 25.6 MB
    float* Kb = (float*)(ws + off); off = align256(off + bufB);
    float* QV = (float*)(ws + off); off = align256(off + 2 * bufB);   // float2 packed Q,V
    float* Sb = (float*)(ws + off); off = align256(off + bufB);
    float* H  = (float*)(ws + off); off = align256(off + bufB);
    unsigned short* Xhi = (unsigned short*)(ws + off); off = align256(off + (size_t)N_PAD * D * 2);
    unsigned short* Xlo = (unsigned short*)(ws + off); off = align256(off + (size_t)N_PAD * D * 2);
    unsigned short* Whi = (unsigned short*)(ws + off); off = align256(off + (size_t)12 * D * D * 2);
    unsigned short* Wlo = (unsigned short*)(ws + off); off = align256(off + (size_t)12 * D * D * 2);
    float* fsum = (float*)(ws + off); off = align256(off + 128 * sizeof(float));
    float* fsq  = (float*)(ws + off); off = align256(off + 128 * sizeof(float));
    int* cnt       = (int*)(ws + off); off = align256(off + (size_t)N_NODES * sizeof(int));
    int* row_start = (int*)(ws + off); off = align256(off + (size_t)(N_NODES + 1) * sizeof(int));
    int* cursor    = (int*)(ws + off); off = align256(off + (size_t)(N_NODES + 1) * sizeof(int));
    int* colI      = (int*)(ws + off); off = align256(off + (size_t)N_EDGES * sizeof(int));
    int* gstart    = (int*)(ws + off); off = align256(off + (N_GRAPHS + 1) * sizeof(int));
    float* psum = (float*)(ws + off); off = align256(off + (size_t)N_GRAPHS * PCHUNK * D * sizeof(float));
    float* pmax = (float*)(ws + off); off = align256(off + (size_t)N_GRAPHS * PCHUNK * D * sizeof(float));
    float* gap = (float*)(ws + off); off = align256(off + (size_t)N_GRAPHS * D * sizeof(float));
    float* gsp = (float*)(ws + off); off = align256(off + (size_t)N_GRAPHS * D * sizeof(float));
    float* h0  = (float*)(ws + off); off = align256(off + (size_t)N_GRAPHS * 256 * sizeof(float));
    float* h1  = (float*)(ws + off); off = align256(off + (size_t)N_GRAPHS * 256 * sizeof(float));
    float* h2  = (float*)(ws + off); off = align256(off + (size_t)N_GRAPHS * 128 * sizeof(float));
    if (off > ws_size) return;

    // ---- one-time prep ----
    hipMemsetAsync(cnt, 0, (size_t)N_NODES * sizeof(int), stream);
    hist_dst<<<(N_EDGES + 255) / 256, 256, 0, stream>>>(dstE, cnt);
    scan_rows<<<1, 1024, 0, stream>>>(cnt, row_start, cursor);
    fill_csr<<<(N_EDGES + 255) / 256, 256, 0, stream>>>(srcE, dstE, cursor, colI);
    find_gstart<<<1, 128, 0, stream>>>(batch, gstart);
    prep_w<<<12 * 128, 128, 0, stream>>>(Wk, Wq, Wv, Ws, Whi, Wlo);
    convert_split<<<(N_PAD * (D / 4) + 255) / 256, 256, 0, stream>>>(x, Xhi, Xlo);

    // ---- 3 conv layers ----
    for (int i = 0; i < 3; ++i) {
        gemm_kqvs_mfma<<<N_PAD / 16, 256, 0, stream>>>(
            Xhi, Xlo,
            Whi + (size_t)i * 4 * D * D, Wlo + (size_t)i * 4 * D * D,
            bk + i * D, bq + i * D, bv + i * D, bs + i * D,
            Kb, QV, Sb);
        aggregate<<<N_NODES / 2, 256, 0, stream>>>(Kb, (const float2*)QV, Sb, row_start, colI, H);
        hipMemsetAsync(fsum, 0, 128 * sizeof(float), stream);
        hipMemsetAsync(fsq, 0, 128 * sizeof(float), stream);
        bn_stats<<<256, 256, 0, stream>>>(H, fsum, fsq);
        bn_apply<<<(N_NODES * D / 4 + 255) / 256, 256, 0, stream>>>(
            H, fsum, fsq, g_cl + i * D, b_cl + i * D);
        if (i < 2) {
            convert_split<<<(N_PAD * (D / 4) + 255) / 256, 256, 0, stream>>>(H, Xhi, Xlo);
        }
    }

    // ---- pooling ----
    pool_partial<<<N_GRAPHS * PCHUNK, 128, 0, stream>>>(H, gstart, psum, pmax);
    pool_combine<<<N_GRAPHS, 128, 0, stream>>>(psum, pmax, gstart, gap, gsp);
    bn_rows<<<1, 128, 0, stream>>>(gap, N_GRAPHS, 128, g_gap, b_gap, h0, 256, 0);
    bn_rows<<<1, 128, 0, stream>>>(gsp, N_GRAPHS, 128, g_gsp, b_gsp, h0, 256, 128);

    // ---- MLP head ----
    gemm_small<<<N_GRAPHS, 256, 0, stream>>>(h0, W1, b1, h1, 256, 256, 1);
    bn_rows<<<1, 256, 0, stream>>>(h1, N_GRAPHS, 256, g1, bt1, h1, 256, 0);
    gemm_small<<<N_GRAPHS, 256, 0, stream>>>(h1, W2, b2, h2, 256, 128, 1);
    bn_rows<<<1, 128, 0, stream>>>(h2, N_GRAPHS, 128, g2, bt2, h2, 128, 0);
    gemm_small<<<N_GRAPHS, 256, 0, stream>>>(h2, Wl, bl, out, 128, 5, 0);
}

// Round 7
// 1094.016 us; speedup vs baseline: 1.3972x; 1.1296x over previous
//
#include <hip/hip_runtime.h>
#include <math.h>

#define N_NODES 50000
#define N_PAD 50048            // padded rows for MFMA tiles (multiple of 128)
#define N_EDGES 800000
#define D 128
#define N_GRAPHS 64
#define EPS 1e-5f
#define PCHUNK 16
#define GSTRIPES 8             // 16-row stripes per GEMM block (128 rows)

typedef __attribute__((ext_vector_type(8))) short bf16x8;
typedef __attribute__((ext_vector_type(4))) float f32x4;

static inline size_t align256(size_t x) { return (x + 255) & ~(size_t)255; }

// ---------- bf16 split helpers (fp32 = hi + lo, each bf16) ----------
__device__ inline unsigned short f2bf(float x) {
    unsigned u = __builtin_bit_cast(unsigned, x);
    u += 0x7FFFu + ((u >> 16) & 1u);      // RNE
    return (unsigned short)(u >> 16);
}
__device__ inline float bf2f(unsigned short h) {
    unsigned u = (unsigned)h << 16;
    return __builtin_bit_cast(float, u);
}

// fast sigmoid: 1/(1+e^-z) with raw v_rcp (sig precision irrelevant at 1ulp)
__device__ inline float fsigmoid(float z) {
    return __builtin_amdgcn_rcpf(1.0f + __expf(-z));
}

// ---------- weight prep: split + transpose ----------
__global__ void prep_w(const float* __restrict__ Wk, const float* __restrict__ Wq,
                       const float* __restrict__ Wv, const float* __restrict__ Ws,
                       unsigned short* __restrict__ Whi, unsigned short* __restrict__ Wlo)
{
    const int j = blockIdx.x & 127;
    const int mat = (blockIdx.x >> 7) & 3;
    const int layer = blockIdx.x >> 9;
    const int k = threadIdx.x;
    const float* Wsrc = (mat == 0) ? Wk : (mat == 1) ? Wq : (mat == 2) ? Wv : Ws;
    const float w = Wsrc[((size_t)layer * D + k) * D + j];
    const unsigned short hi = f2bf(w);
    const unsigned short lo = f2bf(w - bf2f(hi));
    const size_t o = (((size_t)layer * 4 + mat) * D + j) * D + k;
    Whi[o] = hi;
    Wlo[o] = lo;
}

// ---------- split: f32 [N_NODES][128] -> hi/lo bf16 [N_PAD][128] (pad rows = 0) ----------
__global__ void convert_split(const float* __restrict__ X,
                              unsigned short* __restrict__ Xhi, unsigned short* __restrict__ Xlo)
{
    const size_t idx = (size_t)blockIdx.x * blockDim.x + threadIdx.x;  // one per 4 elems
    if (idx >= (size_t)N_PAD * (D / 4)) return;
    const size_t n = idx >> 5;
    float4 v = make_float4(0.f, 0.f, 0.f, 0.f);
    if (n < N_NODES) v = ((const float4*)X)[idx];
    float xv[4] = {v.x, v.y, v.z, v.w};
    unsigned short hi[4], lo[4];
    #pragma unroll
    for (int c = 0; c < 4; ++c) {
        hi[c] = f2bf(xv[c]);
        lo[c] = f2bf(xv[c] - bf2f(hi[c]));
    }
    ((ushort4*)Xhi)[idx] = make_ushort4(hi[0], hi[1], hi[2], hi[3]);
    ((ushort4*)Xlo)[idx] = make_ushort4(lo[0], lo[1], lo[2], lo[3]);
}

// ---------- MFMA GEMM: K,Q,V,S = X @ [Wk|Wq|Wv|Ws] + b (split-bf16 fp32 emu) ----------
// Weight-stationary: block = 512 thr (8 waves); wave = (matrix, 32-col quarter).
// B panel (2 tiles x 4 ksteps x hi/lo) held in registers across GSTRIPES row
// stripes. grid = (N_PAD/(16*GSTRIPES), 2) - blockIdx.y picks the col half.
__global__ void gemm_kqvs_mfma(
    const unsigned short* __restrict__ Xhi, const unsigned short* __restrict__ Xlo,
    const unsigned short* __restrict__ Whi, const unsigned short* __restrict__ Wlo,
    const float* __restrict__ bk, const float* __restrict__ bq,
    const float* __restrict__ bv, const float* __restrict__ bs,
    float* __restrict__ Kb, float* __restrict__ QV, float* __restrict__ Sb)
{
    const int tid = threadIdx.x;
    const int wave = tid >> 6;                 // 0..7
    const int mat = wave >> 1;                 // 0:K 1:Q 2:V 3:S
    const int cq = (wave & 1) + 2 * blockIdx.y; // col quarter 0..3
    const int lane = tid & 63;
    const int l16 = lane & 15;
    const int lhi = lane >> 4;                 // 0..3

    // ---- load B panel once: 2 tiles x 4 ksteps, hi+lo ----
    const unsigned short* wh = Whi + (size_t)mat * D * D;
    const unsigned short* wl = Wlo + (size_t)mat * D * D;
    bf16x8 bh[2][4], bl[2][4];
    #pragma unroll
    for (int t2 = 0; t2 < 2; ++t2) {
        const int tc = (cq * 2 + t2) * 16 + l16;   // output column
        const size_t wb = (size_t)tc * D;
        #pragma unroll
        for (int c = 0; c < 4; ++c) {
            bh[t2][c] = *(const bf16x8*)(wh + wb + c * 32 + lhi * 8);
            bl[t2][c] = *(const bf16x8*)(wl + wb + c * 32 + lhi * 8);
        }
    }

    float* ob;
    const float* bb;
    int stride, offs;
    if (mat == 0)      { ob = Kb;     bb = bk; stride = 1; offs = 0; }
    else if (mat == 1) { ob = QV;     bb = bq; stride = 2; offs = 0; }
    else if (mat == 2) { ob = QV + 1; bb = bv; stride = 2; offs = 0; }
    else               { ob = Sb;     bb = bs; stride = 1; offs = 0; }
    float bias[2];
    #pragma unroll
    for (int t2 = 0; t2 < 2; ++t2) bias[t2] = bb[(cq * 2 + t2) * 16 + l16];

    // ---- stream row stripes ----
    for (int s = 0; s < GSTRIPES; ++s) {
        const int r0 = (blockIdx.x * GSTRIPES + s) * 16;
        bf16x8 ah[4], al[4];
        const size_t arow = (size_t)(r0 + l16) * D;
        #pragma unroll
        for (int c = 0; c < 4; ++c) {
            ah[c] = *(const bf16x8*)(Xhi + arow + c * 32 + lhi * 8);
            al[c] = *(const bf16x8*)(Xlo + arow + c * 32 + lhi * 8);
        }
        f32x4 acc[2];
        acc[0] = (f32x4){0.f, 0.f, 0.f, 0.f};
        acc[1] = (f32x4){0.f, 0.f, 0.f, 0.f};
        #pragma unroll
        for (int t2 = 0; t2 < 2; ++t2) {
            #pragma unroll
            for (int c = 0; c < 4; ++c) {
                acc[t2] = __builtin_amdgcn_mfma_f32_16x16x32_bf16(ah[c], bh[t2][c], acc[t2], 0, 0, 0);
                acc[t2] = __builtin_amdgcn_mfma_f32_16x16x32_bf16(al[c], bh[t2][c], acc[t2], 0, 0, 0);
                acc[t2] = __builtin_amdgcn_mfma_f32_16x16x32_bf16(ah[c], bl[t2][c], acc[t2], 0, 0, 0);
            }
        }
        // C tile layout: col = l16, row = lhi*4 + reg (m89-verified)
        #pragma unroll
        for (int t2 = 0; t2 < 2; ++t2) {
            const int lc = (cq * 2 + t2) * 16 + l16;
            #pragma unroll
            for (int rgi = 0; rgi < 4; ++rgi) {
                const int row = r0 + lhi * 4 + rgi;
                if (row < N_NODES) ob[stride * ((size_t)row * D + lc)] = acc[t2][rgi] + bias[t2];
            }
        }
    }
}

// ---------------- CSR build ----------------
__global__ void hist_dst(const int* __restrict__ dst, int* __restrict__ cnt) {
    int e = blockIdx.x * blockDim.x + threadIdx.x;
    if (e < N_EDGES) atomicAdd(&cnt[dst[e]], 1);
}

__global__ void scan_rows(const int* __restrict__ cnt, int* __restrict__ row_start,
                          int* __restrict__ cursor) {
    __shared__ int partial[1024];
    const int T = 1024;
    const int t = threadIdx.x;
    const int chunk = (N_NODES + T - 1) / T;
    const int lo = t * chunk;
    const int hi = min(lo + chunk, N_NODES);
    int s = 0;
    for (int i = lo; i < hi; ++i) s += cnt[i];
    partial[t] = s;
    __syncthreads();
    for (int off = 1; off < T; off <<= 1) {
        int add = (t >= off) ? partial[t - off] : 0;
        __syncthreads();
        partial[t] += add;
        __syncthreads();
    }
    int base = (t == 0) ? 0 : partial[t - 1];
    for (int i = lo; i < hi; ++i) {
        row_start[i] = base;
        cursor[i] = base;
        base += cnt[i];
    }
    if (t == T - 1) { row_start[N_NODES] = partial[T - 1]; cursor[N_NODES] = partial[T - 1]; }
}

__global__ void fill_csr(const int* __restrict__ src, const int* __restrict__ dst,
                         int* __restrict__ cursor, int* __restrict__ col) {
    int e = blockIdx.x * blockDim.x + threadIdx.x;
    if (e < N_EDGES) {
        int d = dst[e];
        int p = atomicAdd(&cursor[d], 1);
        col[p] = src[e];
    }
}

// ---------------- Edge aggregation + skip + ReLU ----------------
__global__ void aggregate(const float* __restrict__ Kb, const float2* __restrict__ QV,
                          const float* __restrict__ Sb,
                          const int* __restrict__ row_start, const int* __restrict__ col,
                          float* __restrict__ H)
{
    const int tid = threadIdx.x;
    const int node = blockIdx.x * 2 + (tid >> 7);
    const int d = tid & 127;
    const float kd = Kb[(size_t)node * D + d];
    float acc = 0.f;
    const int e0 = row_start[node];
    const int e1 = row_start[node + 1];
    int e = e0;
    for (; e + 4 <= e1; e += 4) {
        const int s0 = col[e + 0];
        const int s1 = col[e + 1];
        const int s2 = col[e + 2];
        const int s3 = col[e + 3];
        const float2 a0 = QV[(size_t)s0 * D + d];
        const float2 a1 = QV[(size_t)s1 * D + d];
        const float2 a2 = QV[(size_t)s2 * D + d];
        const float2 a3 = QV[(size_t)s3 * D + d];
        acc = fmaf(fsigmoid(kd + a0.x), a0.y, acc);
        acc = fmaf(fsigmoid(kd + a1.x), a1.y, acc);
        acc = fmaf(fsigmoid(kd + a2.x), a2.y, acc);
        acc = fmaf(fsigmoid(kd + a3.x), a3.y, acc);
    }
    for (; e < e1; ++e) {
        const int s = col[e];
        const float2 a = QV[(size_t)s * D + d];
        acc = fmaf(fsigmoid(kd + a.x), a.y, acc);
    }
    H[(size_t)node * D + d] = fmaxf(acc + Sb[(size_t)node * D + d], 0.0f);
}

// ---------------- BatchNorm over nodes ----------------
__global__ void bn_stats(const float* __restrict__ H, float* __restrict__ fsum,
                         float* __restrict__ fsq)
{
    __shared__ float s1[256], s2[256];
    const int tid = threadIdx.x;
    const int d = tid & 127;
    const int rowoff = tid >> 7;
    float sum = 0.f, sq = 0.f;
    for (int n = blockIdx.x * 2 + rowoff; n < N_NODES; n += gridDim.x * 2) {
        const float v = H[(size_t)n * D + d];
        sum += v; sq += v * v;
    }
    s1[tid] = sum; s2[tid] = sq;
    __syncthreads();
    if (tid < 128) {
        atomicAdd(&fsum[d], s1[tid] + s1[tid + 128]);
        atomicAdd(&fsq[d],  s2[tid] + s2[tid + 128]);
    }
}

__global__ void bn_apply(float* __restrict__ H, const float* __restrict__ fsum,
                         const float* __restrict__ fsq, const float* __restrict__ g,
                         const float* __restrict__ b)
{
    const int idx = blockIdx.x * blockDim.x + threadIdx.x;
    const int total = N_NODES * D / 4;
    if (idx >= total) return;
    float4 h = ((const float4*)H)[idx];
    float hv[4] = {h.x, h.y, h.z, h.w};
    const int dbase = (idx * 4) & 127;
    float o[4];
    #pragma unroll
    for (int c = 0; c < 4; ++c) {
        const int d = dbase + c;
        const float mu = fsum[d] * (1.0f / N_NODES);
        const float var = fsq[d] * (1.0f / N_NODES) - mu * mu;
        const float sc = g[d] * rsqrtf(var + EPS);
        o[c] = (hv[c] - mu) * sc + b[d];
    }
    ((float4*)H)[idx] = make_float4(o[0], o[1], o[2], o[3]);
}

// ---------------- Pooling ----------------
__global__ void find_gstart(const int* __restrict__ batch, int* __restrict__ gstart) {
    const int g = threadIdx.x;
    if (g > N_GRAPHS) return;
    int lo = 0, hi = N_NODES;
    while (lo < hi) {
        int mid = (lo + hi) >> 1;
        if (batch[mid] < g) lo = mid + 1; else hi = mid;
    }
    gstart[g] = lo;
}

__global__ void pool_partial(const float* __restrict__ X, const int* __restrict__ gstart,
                             float* __restrict__ psum, float* __restrict__ pmax)
{
    const int g = blockIdx.x / PCHUNK;
    const int c = blockIdx.x % PCHUNK;
    const int d = threadIdx.x;
    const int lo = gstart[g], hi = gstart[g + 1];
    float sum = 0.f, mx = -INFINITY;
    for (int n = lo + c; n < hi; n += PCHUNK) {
        const float v = X[(size_t)n * D + d];
        sum += v;
        mx = fmaxf(mx, v);
    }
    psum[(size_t)blockIdx.x * D + d] = sum;
    pmax[(size_t)blockIdx.x * D + d] = mx;
}

__global__ void pool_combine(const float* __restrict__ psum, const float* __restrict__ pmax,
                             const int* __restrict__ gstart,
                             float* __restrict__ gap, float* __restrict__ gsp)
{
    const int g = blockIdx.x;
    const int d = threadIdx.x;
    float sum = 0.f, mx = -INFINITY;
    #pragma unroll
    for (int c = 0; c < PCHUNK; ++c) {
        sum += psum[(size_t)(g * PCHUNK + c) * D + d];
        mx = fmaxf(mx, pmax[(size_t)(g * PCHUNK + c) * D + d]);
    }
    const int cnt = gstart[g + 1] - gstart[g];
    gap[g * D + d] = sum / fmaxf((float)cnt, 1.0f);
    gsp[g * D + d] = (cnt > 0) ? mx : 0.0f;
}

// ---------------- BN over rows (small) ----------------
__global__ void bn_rows(const float* __restrict__ A, int rows, int cols,
                        const float* __restrict__ g, const float* __restrict__ b,
                        float* __restrict__ out, int out_cols, int out_off)
{
    const int c = blockIdx.x * blockDim.x + threadIdx.x;
    if (c >= cols) return;
    float sum = 0.f, sq = 0.f;
    for (int r = 0; r < rows; ++r) {
        const float v = A[r * cols + c];
        sum += v; sq += v * v;
    }
    const float mu = sum / rows;
    const float var = sq / rows - mu * mu;
    const float sc = g[c] * rsqrtf(var + EPS);
    const float sh = b[c] - mu * sc;
    for (int r = 0; r < rows; ++r) {
        out[r * out_cols + out_off + c] = A[r * cols + c] * sc + sh;
    }
}

// ---------------- small GEMM: out = [relu](A @ W + bias) ----------------
__global__ void gemm_small(const float* __restrict__ A, const float* __restrict__ W,
                           const float* __restrict__ bias, float* __restrict__ out,
                           int K, int C, int relu)
{
    __shared__ float as[256];
    const int r = blockIdx.x;
    for (int k = threadIdx.x; k < K; k += blockDim.x) as[k] = A[r * K + k];
    __syncthreads();
    const int j = threadIdx.x;
    if (j < C) {
        float acc = bias[j];
        for (int k = 0; k < K; ++k) acc = fmaf(as[k], W[k * C + j], acc);
        if (relu) acc = fmaxf(acc, 0.f);
        out[r * C + j] = acc;
    }
}

extern "C" void kernel_launch(void* const* d_in, const int* in_sizes, int n_in,
                              void* d_out, int out_size, void* d_ws, size_t ws_size,
                              hipStream_t stream)
{
    const float* x     = (const float*)d_in[0];
    const int*   ei    = (const int*)d_in[1];
    const int*   srcE  = ei;
    const int*   dstE  = ei + N_EDGES;
    const int*   batch = (const int*)d_in[2];
    const float* Wk = (const float*)d_in[3];  const float* bk = (const float*)d_in[4];
    const float* Wq = (const float*)d_in[5];  const float* bq = (const float*)d_in[6];
    const float* Wv = (const float*)d_in[7];  const float* bv = (const float*)d_in[8];
    const float* Ws = (const float*)d_in[9];  const float* bs = (const float*)d_in[10];
    const float* g_cl = (const float*)d_in[11]; const float* b_cl = (const float*)d_in[12];
    const float* g_gap = (const float*)d_in[13]; const float* b_gap = (const float*)d_in[14];
    const float* g_gsp = (const float*)d_in[15]; const float* b_gsp = (const float*)d_in[16];
    const float* W1 = (const float*)d_in[17]; const float* b1 = (const float*)d_in[18];
    const float* g1 = (const float*)d_in[19]; const float* bt1 = (const float*)d_in[20];
    const float* W2 = (const float*)d_in[21]; const float* b2 = (const float*)d_in[22];
    const float* g2 = (const float*)d_in[23]; const float* bt2 = (const float*)d_in[24];
    const float* Wl = (const float*)d_in[25]; const float* bl = (const float*)d_in[26];
    float* out = (float*)d_out;

    // ---- workspace carve ----
    char* ws = (char*)d_ws;
    size_t off = 0;
    const size_t bufB = (size_t)N_NODES * D * sizeof(float);   // 25.6 MB
    float* Kb = (float*)(ws + off); off = align256(off + bufB);
    float* QV = (float*)(ws + off); off = align256(off + 2 * bufB);   // float2 packed Q,V
    float* Sb = (float*)(ws + off); off = align256(off + bufB);
    float* H  = (float*)(ws + off); off = align256(off + bufB);
    unsigned short* Xhi = (unsigned short*)(ws + off); off = align256(off + (size_t)N_PAD * D * 2);
    unsigned short* Xlo = (unsigned short*)(ws + off); off = align256(off + (size_t)N_PAD * D * 2);
    unsigned short* Whi = (unsigned short*)(ws + off); off = align256(off + (size_t)12 * D * D * 2);
    unsigned short* Wlo = (unsigned short*)(ws + off); off = align256(off + (size_t)12 * D * D * 2);
    float* fsum = (float*)(ws + off); off = align256(off + 128 * sizeof(float));
    float* fsq  = (float*)(ws + off); off = align256(off + 128 * sizeof(float));
    int* cnt       = (int*)(ws + off); off = align256(off + (size_t)N_NODES * sizeof(int));
    int* row_start = (int*)(ws + off); off = align256(off + (size_t)(N_NODES + 1) * sizeof(int));
    int* cursor    = (int*)(ws + off); off = align256(off + (size_t)(N_NODES + 1) * sizeof(int));
    int* colI      = (int*)(ws + off); off = align256(off + (size_t)N_EDGES * sizeof(int));
    int* gstart    = (int*)(ws + off); off = align256(off + (N_GRAPHS + 1) * sizeof(int));
    float* psum = (float*)(ws + off); off = align256(off + (size_t)N_GRAPHS * PCHUNK * D * sizeof(float));
    float* pmax = (float*)(ws + off); off = align256(off + (size_t)N_GRAPHS * PCHUNK * D * sizeof(float));
    float* gap = (float*)(ws + off); off = align256(off + (size_t)N_GRAPHS * D * sizeof(float));
    float* gsp = (float*)(ws + off); off = align256(off + (size_t)N_GRAPHS * D * sizeof(float));
    float* h0  = (float*)(ws + off); off = align256(off + (size_t)N_GRAPHS * 256 * sizeof(float));
    float* h1  = (float*)(ws + off); off = align256(off + (size_t)N_GRAPHS * 256 * sizeof(float));
    float* h2  = (float*)(ws + off); off = align256(off + (size_t)N_GRAPHS * 128 * sizeof(float));
    if (off > ws_size) return;

    // ---- one-time prep ----
    hipMemsetAsync(cnt, 0, (size_t)N_NODES * sizeof(int), stream);
    hist_dst<<<(N_EDGES + 255) / 256, 256, 0, stream>>>(dstE, cnt);
    scan_rows<<<1, 1024, 0, stream>>>(cnt, row_start, cursor);
    fill_csr<<<(N_EDGES + 255) / 256, 256, 0, stream>>>(srcE, dstE, cursor, colI);
    find_gstart<<<1, 128, 0, stream>>>(batch, gstart);
    prep_w<<<12 * 128, 128, 0, stream>>>(Wk, Wq, Wv, Ws, Whi, Wlo);
    convert_split<<<(N_PAD * (D / 4) + 255) / 256, 256, 0, stream>>>(x, Xhi, Xlo);

    // ---- 3 conv layers ----
    for (int i = 0; i < 3; ++i) {
        gemm_kqvs_mfma<<<dim3(N_PAD / (16 * GSTRIPES), 2), 512, 0, stream>>>(
            Xhi, Xlo,
            Whi + (size_t)i * 4 * D * D, Wlo + (size_t)i * 4 * D * D,
            bk + i * D, bq + i * D, bv + i * D, bs + i * D,
            Kb, QV, Sb);
        aggregate<<<N_NODES / 2, 256, 0, stream>>>(Kb, (const float2*)QV, Sb, row_start, colI, H);
        hipMemsetAsync(fsum, 0, 128 * sizeof(float), stream);
        hipMemsetAsync(fsq, 0, 128 * sizeof(float), stream);
        bn_stats<<<256, 256, 0, stream>>>(H, fsum, fsq);
        bn_apply<<<(N_NODES * D / 4 + 255) / 256, 256, 0, stream>>>(
            H, fsum, fsq, g_cl + i * D, b_cl + i * D);
        if (i < 2) {
            convert_split<<<(N_PAD * (D / 4) + 255) / 256, 256, 0, stream>>>(H, Xhi, Xlo);
        }
    }

    // ---- pooling ----
    pool_partial<<<N_GRAPHS * PCHUNK, 128, 0, stream>>>(H, gstart, psum, pmax);
    pool_combine<<<N_GRAPHS, 128, 0, stream>>>(psum, pmax, gstart, gap, gsp);
    bn_rows<<<1, 128, 0, stream>>>(gap, N_GRAPHS, 128, g_gap, b_gap, h0, 256, 0);
    bn_rows<<<1, 128, 0, stream>>>(gsp, N_GRAPHS, 128, g_gsp, b_gsp, h0, 256, 128);

    // ---- MLP head ----
    gemm_small<<<N_GRAPHS, 256, 0, stream>>>(h0, W1, b1, h1, 256, 256, 1);
    bn_rows<<<1, 256, 0, stream>>>(h1, N_GRAPHS, 256, g1, bt1, h1, 256, 0);
    gemm_small<<<N_GRAPHS, 256, 0, stream>>>(h1, W2, b2, h2, 256, 128, 1);
    bn_rows<<<1, 128, 0, stream>>>(h2, N_GRAPHS, 128, g2, bt2, h2, 128, 0);
    gemm_small<<<N_GRAPHS, 256, 0, stream>>>(h2, Wl, bl, out, 128, 5, 0);
}

// Round 8
// 964.431 us; speedup vs baseline: 1.5849x; 1.1344x over previous
//
#include <hip/hip_runtime.h>
#include <math.h>

#define N_NODES 50000
#define N_PAD 50048            // padded rows for MFMA tiles (multiple of 128)
#define N_EDGES 800000
#define D 128
#define N_GRAPHS 64
#define EPS 1e-5f
#define PCHUNK 16
#define GSTRIPES 8             // 16-row stripes per GEMM block (128 rows)

typedef __attribute__((ext_vector_type(8))) short bf16x8;
typedef __attribute__((ext_vector_type(4))) float f32x4;
typedef __attribute__((ext_vector_type(2))) _Float16 h16x2;

static inline size_t align256(size_t x) { return (x + 255) & ~(size_t)255; }

// ---------- bf16 split helpers (fp32 = hi + lo, each bf16) ----------
__device__ inline unsigned short f2bf(float x) {
    unsigned u = __builtin_bit_cast(unsigned, x);
    u += 0x7FFFu + ((u >> 16) & 1u);      // RNE
    return (unsigned short)(u >> 16);
}
__device__ inline float bf2f(unsigned short h) {
    unsigned u = (unsigned)h << 16;
    return __builtin_bit_cast(float, u);
}
__device__ inline unsigned short f2h(float x) {   // fp32 -> fp16 RNE
    _Float16 h = (_Float16)x;
    return __builtin_bit_cast(unsigned short, h);
}

// fast sigmoid: 1/(1+e^-z) with raw v_rcp (sig precision irrelevant at 1ulp)
__device__ inline float fsigmoid(float z) {
    return __builtin_amdgcn_rcpf(1.0f + __expf(-z));
}

// ---------- weight prep: split + transpose ----------
__global__ void prep_w(const float* __restrict__ Wk, const float* __restrict__ Wq,
                       const float* __restrict__ Wv, const float* __restrict__ Ws,
                       unsigned short* __restrict__ Whi, unsigned short* __restrict__ Wlo)
{
    const int j = blockIdx.x & 127;
    const int mat = (blockIdx.x >> 7) & 3;
    const int layer = blockIdx.x >> 9;
    const int k = threadIdx.x;
    const float* Wsrc = (mat == 0) ? Wk : (mat == 1) ? Wq : (mat == 2) ? Wv : Ws;
    const float w = Wsrc[((size_t)layer * D + k) * D + j];
    const unsigned short hi = f2bf(w);
    const unsigned short lo = f2bf(w - bf2f(hi));
    const size_t o = (((size_t)layer * 4 + mat) * D + j) * D + k;
    Whi[o] = hi;
    Wlo[o] = lo;
}

// ---------- split: f32 [N_NODES][128] -> hi/lo bf16 [N_PAD][128] (pad rows = 0) ----------
__global__ void convert_split(const float* __restrict__ X,
                              unsigned short* __restrict__ Xhi, unsigned short* __restrict__ Xlo)
{
    const size_t idx = (size_t)blockIdx.x * blockDim.x + threadIdx.x;  // one per 4 elems
    if (idx >= (size_t)N_PAD * (D / 4)) return;
    const size_t n = idx >> 5;
    float4 v = make_float4(0.f, 0.f, 0.f, 0.f);
    if (n < N_NODES) v = ((const float4*)X)[idx];
    float xv[4] = {v.x, v.y, v.z, v.w};
    unsigned short hi[4], lo[4];
    #pragma unroll
    for (int c = 0; c < 4; ++c) {
        hi[c] = f2bf(xv[c]);
        lo[c] = f2bf(xv[c] - bf2f(hi[c]));
    }
    ((ushort4*)Xhi)[idx] = make_ushort4(hi[0], hi[1], hi[2], hi[3]);
    ((ushort4*)Xlo)[idx] = make_ushort4(lo[0], lo[1], lo[2], lo[3]);
}

// ---------- MFMA GEMM: K,Q,V,S = X @ [Wk|Wq|Wv|Ws] + b (split-bf16 fp32 emu) ----------
// Weight-stationary: block = 512 thr (8 waves); wave = (matrix, 32-col quarter).
// B panel held in registers across GSTRIPES row stripes.
// K,S -> fp32 buffers. Q,V -> packed fp16 half2 (Q low, V high halfword).
__global__ void gemm_kqvs_mfma(
    const unsigned short* __restrict__ Xhi, const unsigned short* __restrict__ Xlo,
    const unsigned short* __restrict__ Whi, const unsigned short* __restrict__ Wlo,
    const float* __restrict__ bk, const float* __restrict__ bq,
    const float* __restrict__ bv, const float* __restrict__ bs,
    float* __restrict__ Kb, unsigned short* __restrict__ QVh, float* __restrict__ Sb)
{
    const int tid = threadIdx.x;
    const int wave = tid >> 6;                 // 0..7
    const int mat = wave >> 1;                 // 0:K 1:Q 2:V 3:S
    const int cq = (wave & 1) + 2 * blockIdx.y; // col quarter 0..3
    const int lane = tid & 63;
    const int l16 = lane & 15;
    const int lhi = lane >> 4;                 // 0..3

    // ---- load B panel once: 2 tiles x 4 ksteps, hi+lo ----
    const unsigned short* wh = Whi + (size_t)mat * D * D;
    const unsigned short* wl = Wlo + (size_t)mat * D * D;
    bf16x8 bh[2][4], bl[2][4];
    #pragma unroll
    for (int t2 = 0; t2 < 2; ++t2) {
        const int tc = (cq * 2 + t2) * 16 + l16;   // output column
        const size_t wb = (size_t)tc * D;
        #pragma unroll
        for (int c = 0; c < 4; ++c) {
            bh[t2][c] = *(const bf16x8*)(wh + wb + c * 32 + lhi * 8);
            bl[t2][c] = *(const bf16x8*)(wl + wb + c * 32 + lhi * 8);
        }
    }

    const float* bb = (mat == 0) ? bk : (mat == 1) ? bq : (mat == 2) ? bv : bs;
    float bias[2];
    #pragma unroll
    for (int t2 = 0; t2 < 2; ++t2) bias[t2] = bb[(cq * 2 + t2) * 16 + l16];

    // ---- stream row stripes ----
    for (int s = 0; s < GSTRIPES; ++s) {
        const int r0 = (blockIdx.x * GSTRIPES + s) * 16;
        bf16x8 ah[4], al[4];
        const size_t arow = (size_t)(r0 + l16) * D;
        #pragma unroll
        for (int c = 0; c < 4; ++c) {
            ah[c] = *(const bf16x8*)(Xhi + arow + c * 32 + lhi * 8);
            al[c] = *(const bf16x8*)(Xlo + arow + c * 32 + lhi * 8);
        }
        f32x4 acc[2];
        acc[0] = (f32x4){0.f, 0.f, 0.f, 0.f};
        acc[1] = (f32x4){0.f, 0.f, 0.f, 0.f};
        #pragma unroll
        for (int t2 = 0; t2 < 2; ++t2) {
            #pragma unroll
            for (int c = 0; c < 4; ++c) {
                acc[t2] = __builtin_amdgcn_mfma_f32_16x16x32_bf16(ah[c], bh[t2][c], acc[t2], 0, 0, 0);
                acc[t2] = __builtin_amdgcn_mfma_f32_16x16x32_bf16(al[c], bh[t2][c], acc[t2], 0, 0, 0);
                acc[t2] = __builtin_amdgcn_mfma_f32_16x16x32_bf16(ah[c], bl[t2][c], acc[t2], 0, 0, 0);
            }
        }
        // C tile layout: col = l16, row = lhi*4 + reg (m89-verified)
        if (mat == 0 || mat == 3) {
            float* ob = (mat == 0) ? Kb : Sb;
            #pragma unroll
            for (int t2 = 0; t2 < 2; ++t2) {
                const int lc = (cq * 2 + t2) * 16 + l16;
                #pragma unroll
                for (int rgi = 0; rgi < 4; ++rgi) {
                    const int row = r0 + lhi * 4 + rgi;
                    if (row < N_NODES) ob[(size_t)row * D + lc] = acc[t2][rgi] + bias[t2];
                }
            }
        } else {
            // Q -> even halfword, V -> odd halfword of the packed QV dword
            unsigned short* base = QVh + ((mat == 2) ? 1 : 0);
            #pragma unroll
            for (int t2 = 0; t2 < 2; ++t2) {
                const int lc = (cq * 2 + t2) * 16 + l16;
                #pragma unroll
                for (int rgi = 0; rgi < 4; ++rgi) {
                    const int row = r0 + lhi * 4 + rgi;
                    if (row < N_NODES) base[2 * ((size_t)row * D + lc)] = f2h(acc[t2][rgi] + bias[t2]);
                }
            }
        }
    }
}

// ---------------- CSR build ----------------
__global__ void hist_dst(const int* __restrict__ dst, int* __restrict__ cnt) {
    int e = blockIdx.x * blockDim.x + threadIdx.x;
    if (e < N_EDGES) atomicAdd(&cnt[dst[e]], 1);
}

__global__ void scan_rows(const int* __restrict__ cnt, int* __restrict__ row_start,
                          int* __restrict__ cursor) {
    __shared__ int partial[1024];
    const int T = 1024;
    const int t = threadIdx.x;
    const int chunk = (N_NODES + T - 1) / T;
    const int lo = t * chunk;
    const int hi = min(lo + chunk, N_NODES);
    int s = 0;
    for (int i = lo; i < hi; ++i) s += cnt[i];
    partial[t] = s;
    __syncthreads();
    for (int off = 1; off < T; off <<= 1) {
        int add = (t >= off) ? partial[t - off] : 0;
        __syncthreads();
        partial[t] += add;
        __syncthreads();
    }
    int base = (t == 0) ? 0 : partial[t - 1];
    for (int i = lo; i < hi; ++i) {
        row_start[i] = base;
        cursor[i] = base;
        base += cnt[i];
    }
    if (t == T - 1) { row_start[N_NODES] = partial[T - 1]; cursor[N_NODES] = partial[T - 1]; }
}

__global__ void fill_csr(const int* __restrict__ src, const int* __restrict__ dst,
                         int* __restrict__ cursor, int* __restrict__ col) {
    int e = blockIdx.x * blockDim.x + threadIdx.x;
    if (e < N_EDGES) {
        int d = dst[e];
        int p = atomicAdd(&cursor[d], 1);
        col[p] = src[e];
    }
}

// ---------------- Edge aggregation + skip + ReLU ----------------
// block 256 threads = 2 dst nodes; 4-deep unroll keeps >=4 packed gathers in flight.
__global__ void aggregate(const float* __restrict__ Kb, const unsigned int* __restrict__ QV,
                          const float* __restrict__ Sb,
                          const int* __restrict__ row_start, const int* __restrict__ col,
                          float* __restrict__ H)
{
    const int tid = threadIdx.x;
    const int node = blockIdx.x * 2 + (tid >> 7);
    const int d = tid & 127;
    const float kd = Kb[(size_t)node * D + d];
    float acc = 0.f;
    const int e0 = row_start[node];
    const int e1 = row_start[node + 1];
    int e = e0;
    for (; e + 4 <= e1; e += 4) {
        const int s0 = col[e + 0];
        const int s1 = col[e + 1];
        const int s2 = col[e + 2];
        const int s3 = col[e + 3];
        const unsigned u0 = QV[(size_t)s0 * D + d];
        const unsigned u1 = QV[(size_t)s1 * D + d];
        const unsigned u2 = QV[(size_t)s2 * D + d];
        const unsigned u3 = QV[(size_t)s3 * D + d];
        const h16x2 a0 = __builtin_bit_cast(h16x2, u0);
        const h16x2 a1 = __builtin_bit_cast(h16x2, u1);
        const h16x2 a2 = __builtin_bit_cast(h16x2, u2);
        const h16x2 a3 = __builtin_bit_cast(h16x2, u3);
        acc = fmaf(fsigmoid(kd + (float)a0[0]), (float)a0[1], acc);
        acc = fmaf(fsigmoid(kd + (float)a1[0]), (float)a1[1], acc);
        acc = fmaf(fsigmoid(kd + (float)a2[0]), (float)a2[1], acc);
        acc = fmaf(fsigmoid(kd + (float)a3[0]), (float)a3[1], acc);
    }
    for (; e < e1; ++e) {
        const int s = col[e];
        const h16x2 a = __builtin_bit_cast(h16x2, QV[(size_t)s * D + d]);
        acc = fmaf(fsigmoid(kd + (float)a[0]), (float)a[1], acc);
    }
    H[(size_t)node * D + d] = fmaxf(acc + Sb[(size_t)node * D + d], 0.0f);
}

// ---------------- BatchNorm over nodes ----------------
__global__ void bn_stats(const float* __restrict__ H, float* __restrict__ fsum,
                         float* __restrict__ fsq)
{
    __shared__ float s1[256], s2[256];
    const int tid = threadIdx.x;
    const int d = tid & 127;
    const int rowoff = tid >> 7;
    float sum = 0.f, sq = 0.f;
    for (int n = blockIdx.x * 2 + rowoff; n < N_NODES; n += gridDim.x * 2) {
        const float v = H[(size_t)n * D + d];
        sum += v; sq += v * v;
    }
    s1[tid] = sum; s2[tid] = sq;
    __syncthreads();
    if (tid < 128) {
        atomicAdd(&fsum[d], s1[tid] + s1[tid + 128]);
        atomicAdd(&fsq[d],  s2[tid] + s2[tid + 128]);
    }
}

__global__ void bn_apply(float* __restrict__ H, const float* __restrict__ fsum,
                         const float* __restrict__ fsq, const float* __restrict__ g,
                         const float* __restrict__ b)
{
    const int idx = blockIdx.x * blockDim.x + threadIdx.x;
    const int total = N_NODES * D / 4;
    if (idx >= total) return;
    float4 h = ((const float4*)H)[idx];
    float hv[4] = {h.x, h.y, h.z, h.w};
    const int dbase = (idx * 4) & 127;
    float o[4];
    #pragma unroll
    for (int c = 0; c < 4; ++c) {
        const int d = dbase + c;
        const float mu = fsum[d] * (1.0f / N_NODES);
        const float var = fsq[d] * (1.0f / N_NODES) - mu * mu;
        const float sc = g[d] * rsqrtf(var + EPS);
        o[c] = (hv[c] - mu) * sc + b[d];
    }
    ((float4*)H)[idx] = make_float4(o[0], o[1], o[2], o[3]);
}

// ---------------- Pooling ----------------
__global__ void find_gstart(const int* __restrict__ batch, int* __restrict__ gstart) {
    const int g = threadIdx.x;
    if (g > N_GRAPHS) return;
    int lo = 0, hi = N_NODES;
    while (lo < hi) {
        int mid = (lo + hi) >> 1;
        if (batch[mid] < g) lo = mid + 1; else hi = mid;
    }
    gstart[g] = lo;
}

__global__ void pool_partial(const float* __restrict__ X, const int* __restrict__ gstart,
                             float* __restrict__ psum, float* __restrict__ pmax)
{
    const int g = blockIdx.x / PCHUNK;
    const int c = blockIdx.x % PCHUNK;
    const int d = threadIdx.x;
    const int lo = gstart[g], hi = gstart[g + 1];
    float sum = 0.f, mx = -INFINITY;
    for (int n = lo + c; n < hi; n += PCHUNK) {
        const float v = X[(size_t)n * D + d];
        sum += v;
        mx = fmaxf(mx, v);
    }
    psum[(size_t)blockIdx.x * D + d] = sum;
    pmax[(size_t)blockIdx.x * D + d] = mx;
}

__global__ void pool_combine(const float* __restrict__ psum, const float* __restrict__ pmax,
                             const int* __restrict__ gstart,
                             float* __restrict__ gap, float* __restrict__ gsp)
{
    const int g = blockIdx.x;
    const int d = threadIdx.x;
    float sum = 0.f, mx = -INFINITY;
    #pragma unroll
    for (int c = 0; c < PCHUNK; ++c) {
        sum += psum[(size_t)(g * PCHUNK + c) * D + d];
        mx = fmaxf(mx, pmax[(size_t)(g * PCHUNK + c) * D + d]);
    }
    const int cnt = gstart[g + 1] - gstart[g];
    gap[g * D + d] = sum / fmaxf((float)cnt, 1.0f);
    gsp[g * D + d] = (cnt > 0) ? mx : 0.0f;
}

// ---------------- BN over rows (small) ----------------
__global__ void bn_rows(const float* __restrict__ A, int rows, int cols,
                        const float* __restrict__ g, const float* __restrict__ b,
                        float* __restrict__ out, int out_cols, int out_off)
{
    const int c = blockIdx.x * blockDim.x + threadIdx.x;
    if (c >= cols) return;
    float sum = 0.f, sq = 0.f;
    for (int r = 0; r < rows; ++r) {
        const float v = A[r * cols + c];
        sum += v; sq += v * v;
    }
    const float mu = sum / rows;
    const float var = sq / rows - mu * mu;
    const float sc = g[c] * rsqrtf(var + EPS);
    const float sh = b[c] - mu * sc;
    for (int r = 0; r < rows; ++r) {
        out[r * out_cols + out_off + c] = A[r * cols + c] * sc + sh;
    }
}

// ---------------- small GEMM: out = [relu](A @ W + bias) ----------------
__global__ void gemm_small(const float* __restrict__ A, const float* __restrict__ W,
                           const float* __restrict__ bias, float* __restrict__ out,
                           int K, int C, int relu)
{
    __shared__ float as[256];
    const int r = blockIdx.x;
    for (int k = threadIdx.x; k < K; k += blockDim.x) as[k] = A[r * K + k];
    __syncthreads();
    const int j = threadIdx.x;
    if (j < C) {
        float acc = bias[j];
        for (int k = 0; k < K; ++k) acc = fmaf(as[k], W[k * C + j], acc);
        if (relu) acc = fmaxf(acc, 0.f);
        out[r * C + j] = acc;
    }
}

extern "C" void kernel_launch(void* const* d_in, const int* in_sizes, int n_in,
                              void* d_out, int out_size, void* d_ws, size_t ws_size,
                              hipStream_t stream)
{
    const float* x     = (const float*)d_in[0];
    const int*   ei    = (const int*)d_in[1];
    const int*   srcE  = ei;
    const int*   dstE  = ei + N_EDGES;
    const int*   batch = (const int*)d_in[2];
    const float* Wk = (const float*)d_in[3];  const float* bk = (const float*)d_in[4];
    const float* Wq = (const float*)d_in[5];  const float* bq = (const float*)d_in[6];
    const float* Wv = (const float*)d_in[7];  const float* bv = (const float*)d_in[8];
    const float* Ws = (const float*)d_in[9];  const float* bs = (const float*)d_in[10];
    const float* g_cl = (const float*)d_in[11]; const float* b_cl = (const float*)d_in[12];
    const float* g_gap = (const float*)d_in[13]; const float* b_gap = (const float*)d_in[14];
    const float* g_gsp = (const float*)d_in[15]; const float* b_gsp = (const float*)d_in[16];
    const float* W1 = (const float*)d_in[17]; const float* b1 = (const float*)d_in[18];
    const float* g1 = (const float*)d_in[19]; const float* bt1 = (const float*)d_in[20];
    const float* W2 = (const float*)d_in[21]; const float* b2 = (const float*)d_in[22];
    const float* g2 = (const float*)d_in[23]; const float* bt2 = (const float*)d_in[24];
    const float* Wl = (const float*)d_in[25]; const float* bl = (const float*)d_in[26];
    float* out = (float*)d_out;

    // ---- workspace carve ----
    char* ws = (char*)d_ws;
    size_t off = 0;
    const size_t bufB = (size_t)N_NODES * D * sizeof(float);   // 25.6 MB
    float* Kb = (float*)(ws + off); off = align256(off + bufB);
    unsigned short* QVh = (unsigned short*)(ws + off); off = align256(off + bufB); // half2 packed Q,V
    float* Sb = (float*)(ws + off); off = align256(off + bufB);
    float* H  = (float*)(ws + off); off = align256(off + bufB);
    unsigned short* Xhi = (unsigned short*)(ws + off); off = align256(off + (size_t)N_PAD * D * 2);
    unsigned short* Xlo = (unsigned short*)(ws + off); off = align256(off + (size_t)N_PAD * D * 2);
    unsigned short* Whi = (unsigned short*)(ws + off); off = align256(off + (size_t)12 * D * D * 2);
    unsigned short* Wlo = (unsigned short*)(ws + off); off = align256(off + (size_t)12 * D * D * 2);
    float* fsum = (float*)(ws + off); off = align256(off + 128 * sizeof(float));
    float* fsq  = (float*)(ws + off); off = align256(off + 128 * sizeof(float));
    int* cnt       = (int*)(ws + off); off = align256(off + (size_t)N_NODES * sizeof(int));
    int* row_start = (int*)(ws + off); off = align256(off + (size_t)(N_NODES + 1) * sizeof(int));
    int* cursor    = (int*)(ws + off); off = align256(off + (size_t)(N_NODES + 1) * sizeof(int));
    int* colI      = (int*)(ws + off); off = align256(off + (size_t)N_EDGES * sizeof(int));
    int* gstart    = (int*)(ws + off); off = align256(off + (N_GRAPHS + 1) * sizeof(int));
    float* psum = (float*)(ws + off); off = align256(off + (size_t)N_GRAPHS * PCHUNK * D * sizeof(float));
    float* pmax = (float*)(ws + off); off = align256(off + (size_t)N_GRAPHS * PCHUNK * D * sizeof(float));
    float* gap = (float*)(ws + off); off = align256(off + (size_t)N_GRAPHS * D * sizeof(float));
    float* gsp = (float*)(ws + off); off = align256(off + (size_t)N_GRAPHS * D * sizeof(float));
    float* h0  = (float*)(ws + off); off = align256(off + (size_t)N_GRAPHS * 256 * sizeof(float));
    float* h1  = (float*)(ws + off); off = align256(off + (size_t)N_GRAPHS * 256 * sizeof(float));
    float* h2  = (float*)(ws + off); off = align256(off + (size_t)N_GRAPHS * 128 * sizeof(float));
    if (off > ws_size) return;

    // ---- one-time prep ----
    hipMemsetAsync(cnt, 0, (size_t)N_NODES * sizeof(int), stream);
    hist_dst<<<(N_EDGES + 255) / 256, 256, 0, stream>>>(dstE, cnt);
    scan_rows<<<1, 1024, 0, stream>>>(cnt, row_start, cursor);
    fill_csr<<<(N_EDGES + 255) / 256, 256, 0, stream>>>(srcE, dstE, cursor, colI);
    find_gstart<<<1, 128, 0, stream>>>(batch, gstart);
    prep_w<<<12 * 128, 128, 0, stream>>>(Wk, Wq, Wv, Ws, Whi, Wlo);
    convert_split<<<(N_PAD * (D / 4) + 255) / 256, 256, 0, stream>>>(x, Xhi, Xlo);

    // ---- 3 conv layers ----
    for (int i = 0; i < 3; ++i) {
        gemm_kqvs_mfma<<<dim3(N_PAD / (16 * GSTRIPES), 2), 512, 0, stream>>>(
            Xhi, Xlo,
            Whi + (size_t)i * 4 * D * D, Wlo + (size_t)i * 4 * D * D,
            bk + i * D, bq + i * D, bv + i * D, bs + i * D,
            Kb, QVh, Sb);
        aggregate<<<N_NODES / 2, 256, 0, stream>>>(Kb, (const unsigned int*)QVh, Sb, row_start, colI, H);
        hipMemsetAsync(fsum, 0, 128 * sizeof(float), stream);
        hipMemsetAsync(fsq, 0, 128 * sizeof(float), stream);
        bn_stats<<<256, 256, 0, stream>>>(H, fsum, fsq);
        bn_apply<<<(N_NODES * D / 4 + 255) / 256, 256, 0, stream>>>(
            H, fsum, fsq, g_cl + i * D, b_cl + i * D);
        if (i < 2) {
            convert_split<<<(N_PAD * (D / 4) + 255) / 256, 256, 0, stream>>>(H, Xhi, Xlo);
        }
    }

    // ---- pooling ----
    pool_partial<<<N_GRAPHS * PCHUNK, 128, 0, stream>>>(H, gstart, psum, pmax);
    pool_combine<<<N_GRAPHS, 128, 0, stream>>>(psum, pmax, gstart, gap, gsp);
    bn_rows<<<1, 128, 0, stream>>>(gap, N_GRAPHS, 128, g_gap, b_gap, h0, 256, 0);
    bn_rows<<<1, 128, 0, stream>>>(gsp, N_GRAPHS, 128, g_gsp, b_gsp, h0, 256, 128);

    // ---- MLP head ----
    gemm_small<<<N_GRAPHS, 256, 0, stream>>>(h0, W1, b1, h1, 256, 256, 1);
    bn_rows<<<1, 256, 0, stream>>>(h1, N_GRAPHS, 256, g1, bt1, h1, 256, 0);
    gemm_small<<<N_GRAPHS, 256, 0, stream>>>(h1, W2, b2, h2, 256, 128, 1);
    bn_rows<<<1, 128, 0, stream>>>(h2, N_GRAPHS, 128, g2, bt2, h2, 128, 0);
    gemm_small<<<N_GRAPHS, 256, 0, stream>>>(h2, Wl, bl, out, 128, 5, 0);
}

// Round 9
// 869.178 us; speedup vs baseline: 1.7586x; 1.1096x over previous
//
#include <hip/hip_runtime.h>
#include <math.h>

#define N_NODES 50000
#define N_PAD 50048            // padded rows for MFMA tiles (multiple of 128)
#define N_EDGES 800000
#define D 128
#define N_GRAPHS 64
#define EPS 1e-5f
#define PCHUNK 16
#define GSTRIPES 8             // 16-row stripes per GEMM block (128 rows)
#define SCAN_NB 196            // ceil(N_NODES/256)

typedef __attribute__((ext_vector_type(8))) short bf16x8;
typedef __attribute__((ext_vector_type(4))) float f32x4;
typedef __attribute__((ext_vector_type(2))) _Float16 h16x2;

static inline size_t align256(size_t x) { return (x + 255) & ~(size_t)255; }

// ---------- bf16 split helpers (fp32 = hi + lo, each bf16) ----------
__device__ inline unsigned short f2bf(float x) {
    unsigned u = __builtin_bit_cast(unsigned, x);
    u += 0x7FFFu + ((u >> 16) & 1u);      // RNE
    return (unsigned short)(u >> 16);
}
__device__ inline float bf2f(unsigned short h) {
    unsigned u = (unsigned)h << 16;
    return __builtin_bit_cast(float, u);
}
__device__ inline unsigned short f2h(float x) {   // fp32 -> fp16 RNE
    _Float16 h = (_Float16)x;
    return __builtin_bit_cast(unsigned short, h);
}

// fast sigmoid: 1/(1+e^-z) with raw v_rcp (sig precision irrelevant at 1ulp)
__device__ inline float fsigmoid(float z) {
    return __builtin_amdgcn_rcpf(1.0f + __expf(-z));
}

// ---------- weight prep: split + transpose ----------
__global__ void prep_w(const float* __restrict__ Wk, const float* __restrict__ Wq,
                       const float* __restrict__ Wv, const float* __restrict__ Ws,
                       unsigned short* __restrict__ Whi, unsigned short* __restrict__ Wlo)
{
    const int j = blockIdx.x & 127;
    const int mat = (blockIdx.x >> 7) & 3;
    const int layer = blockIdx.x >> 9;
    const int k = threadIdx.x;
    const float* Wsrc = (mat == 0) ? Wk : (mat == 1) ? Wq : (mat == 2) ? Wv : Ws;
    const float w = Wsrc[((size_t)layer * D + k) * D + j];
    const unsigned short hi = f2bf(w);
    const unsigned short lo = f2bf(w - bf2f(hi));
    const size_t o = (((size_t)layer * 4 + mat) * D + j) * D + k;
    Whi[o] = hi;
    Wlo[o] = lo;
}

// ---------- split: f32 [N_NODES][128] -> hi/lo bf16 [N_PAD][128] (pad rows = 0) ----------
__global__ void convert_split(const float* __restrict__ X,
                              unsigned short* __restrict__ Xhi, unsigned short* __restrict__ Xlo)
{
    const size_t idx = (size_t)blockIdx.x * blockDim.x + threadIdx.x;  // one per 4 elems
    if (idx >= (size_t)N_PAD * (D / 4)) return;
    const size_t n = idx >> 5;
    float4 v = make_float4(0.f, 0.f, 0.f, 0.f);
    if (n < N_NODES) v = ((const float4*)X)[idx];
    float xv[4] = {v.x, v.y, v.z, v.w};
    unsigned short hi[4], lo[4];
    #pragma unroll
    for (int c = 0; c < 4; ++c) {
        hi[c] = f2bf(xv[c]);
        lo[c] = f2bf(xv[c] - bf2f(hi[c]));
    }
    ((ushort4*)Xhi)[idx] = make_ushort4(hi[0], hi[1], hi[2], hi[3]);
    ((ushort4*)Xlo)[idx] = make_ushort4(lo[0], lo[1], lo[2], lo[3]);
}

// ---------- MFMA GEMM: K,Q,V,S = X @ [Wk|Wq|Wv|Ws] + b (split-bf16 fp32 emu) ----------
// Weight-stationary: block = 512 thr (8 waves); wave = (matrix, 32-col quarter).
// B panel held in registers across GSTRIPES row stripes.
// K,S -> fp32 buffers. Q,V -> packed fp16 half2 (Q low, V high halfword).
__global__ void gemm_kqvs_mfma(
    const unsigned short* __restrict__ Xhi, const unsigned short* __restrict__ Xlo,
    const unsigned short* __restrict__ Whi, const unsigned short* __restrict__ Wlo,
    const float* __restrict__ bk, const float* __restrict__ bq,
    const float* __restrict__ bv, const float* __restrict__ bs,
    float* __restrict__ Kb, unsigned short* __restrict__ QVh, float* __restrict__ Sb)
{
    const int tid = threadIdx.x;
    const int wave = tid >> 6;                 // 0..7
    const int mat = wave >> 1;                 // 0:K 1:Q 2:V 3:S
    const int cq = (wave & 1) + 2 * blockIdx.y; // col quarter 0..3
    const int lane = tid & 63;
    const int l16 = lane & 15;
    const int lhi = lane >> 4;                 // 0..3

    // ---- load B panel once: 2 tiles x 4 ksteps, hi+lo ----
    const unsigned short* wh = Whi + (size_t)mat * D * D;
    const unsigned short* wl = Wlo + (size_t)mat * D * D;
    bf16x8 bh[2][4], bl[2][4];
    #pragma unroll
    for (int t2 = 0; t2 < 2; ++t2) {
        const int tc = (cq * 2 + t2) * 16 + l16;   // output column
        const size_t wb = (size_t)tc * D;
        #pragma unroll
        for (int c = 0; c < 4; ++c) {
            bh[t2][c] = *(const bf16x8*)(wh + wb + c * 32 + lhi * 8);
            bl[t2][c] = *(const bf16x8*)(wl + wb + c * 32 + lhi * 8);
        }
    }

    const float* bb = (mat == 0) ? bk : (mat == 1) ? bq : (mat == 2) ? bv : bs;
    float bias[2];
    #pragma unroll
    for (int t2 = 0; t2 < 2; ++t2) bias[t2] = bb[(cq * 2 + t2) * 16 + l16];

    // ---- stream row stripes ----
    for (int s = 0; s < GSTRIPES; ++s) {
        const int r0 = (blockIdx.x * GSTRIPES + s) * 16;
        bf16x8 ah[4], al[4];
        const size_t arow = (size_t)(r0 + l16) * D;
        #pragma unroll
        for (int c = 0; c < 4; ++c) {
            ah[c] = *(const bf16x8*)(Xhi + arow + c * 32 + lhi * 8);
            al[c] = *(const bf16x8*)(Xlo + arow + c * 32 + lhi * 8);
        }
        f32x4 acc[2];
        acc[0] = (f32x4){0.f, 0.f, 0.f, 0.f};
        acc[1] = (f32x4){0.f, 0.f, 0.f, 0.f};
        #pragma unroll
        for (int t2 = 0; t2 < 2; ++t2) {
            #pragma unroll
            for (int c = 0; c < 4; ++c) {
                acc[t2] = __builtin_amdgcn_mfma_f32_16x16x32_bf16(ah[c], bh[t2][c], acc[t2], 0, 0, 0);
                acc[t2] = __builtin_amdgcn_mfma_f32_16x16x32_bf16(al[c], bh[t2][c], acc[t2], 0, 0, 0);
                acc[t2] = __builtin_amdgcn_mfma_f32_16x16x32_bf16(ah[c], bl[t2][c], acc[t2], 0, 0, 0);
            }
        }
        // C tile layout: col = l16, row = lhi*4 + reg (m89-verified)
        if (mat == 0 || mat == 3) {
            float* ob = (mat == 0) ? Kb : Sb;
            #pragma unroll
            for (int t2 = 0; t2 < 2; ++t2) {
                const int lc = (cq * 2 + t2) * 16 + l16;
                #pragma unroll
                for (int rgi = 0; rgi < 4; ++rgi) {
                    const int row = r0 + lhi * 4 + rgi;
                    if (row < N_NODES) ob[(size_t)row * D + lc] = acc[t2][rgi] + bias[t2];
                }
            }
        } else {
            // Q -> even halfword, V -> odd halfword of the packed QV dword
            unsigned short* base = QVh + ((mat == 2) ? 1 : 0);
            #pragma unroll
            for (int t2 = 0; t2 < 2; ++t2) {
                const int lc = (cq * 2 + t2) * 16 + l16;
                #pragma unroll
                for (int rgi = 0; rgi < 4; ++rgi) {
                    const int row = r0 + lhi * 4 + rgi;
                    if (row < N_NODES) base[2 * ((size_t)row * D + lc)] = f2h(acc[t2][rgi] + bias[t2]);
                }
            }
        }
    }
}

// ---------------- CSR build ----------------
__global__ void hist_dst(const int* __restrict__ dst, int* __restrict__ cnt) {
    int e = blockIdx.x * blockDim.x + threadIdx.x;
    if (e < N_EDGES) atomicAdd(&cnt[dst[e]], 1);
}

// hierarchical exclusive scan of cnt[0..N_NODES) -> row_start, cursor
// A: per-block (256-wide) sums
__global__ void scan_block_sums(const int* __restrict__ cnt, int* __restrict__ bsum) {
    __shared__ int s[256];
    const int t = threadIdx.x;
    const int i = blockIdx.x * 256 + t;
    s[t] = (i < N_NODES) ? cnt[i] : 0;
    __syncthreads();
    #pragma unroll
    for (int off = 128; off > 0; off >>= 1) {
        if (t < off) s[t] += s[t + off];
        __syncthreads();
    }
    if (t == 0) bsum[blockIdx.x] = s[0];
}

// B: scan the SCAN_NB block sums (single block)
__global__ void scan_block_offsets(const int* __restrict__ bsum, int* __restrict__ boff) {
    __shared__ int s[256];
    const int t = threadIdx.x;
    s[t] = (t < SCAN_NB) ? bsum[t] : 0;
    __syncthreads();
    for (int off = 1; off < 256; off <<= 1) {
        const int add = (t >= off) ? s[t - off] : 0;
        __syncthreads();
        s[t] += add;
        __syncthreads();
    }
    if (t < SCAN_NB) boff[t] = (t == 0) ? 0 : s[t - 1];   // exclusive
}

// C: intra-block scan + block offset -> row_start, cursor
__global__ void scan_final(const int* __restrict__ cnt, const int* __restrict__ boff,
                           int* __restrict__ row_start, int* __restrict__ cursor) {
    __shared__ int s[256];
    const int t = threadIdx.x;
    const int i = blockIdx.x * 256 + t;
    const int v = (i < N_NODES) ? cnt[i] : 0;
    s[t] = v;
    __syncthreads();
    for (int off = 1; off < 256; off <<= 1) {
        const int add = (t >= off) ? s[t - off] : 0;
        __syncthreads();
        s[t] += add;
        __syncthreads();
    }
    if (i < N_NODES) {
        const int excl = boff[blockIdx.x] + s[t] - v;
        row_start[i] = excl;
        cursor[i] = excl;
    }
    if (i == N_NODES - 1) {
        row_start[N_NODES] = N_EDGES;   // every edge has a dst
        cursor[N_NODES] = N_EDGES;
    }
}

__global__ void fill_csr(const int* __restrict__ src, const int* __restrict__ dst,
                         int* __restrict__ cursor, int* __restrict__ col) {
    int e = blockIdx.x * blockDim.x + threadIdx.x;
    if (e < N_EDGES) {
        int d = dst[e];
        int p = atomicAdd(&cursor[d], 1);
        col[p] = src[e];
    }
}

// ---------------- Edge aggregation + skip + ReLU ----------------
// block 256 threads = 2 dst nodes; 4-deep unroll keeps >=4 packed gathers in flight.
__global__ void aggregate(const float* __restrict__ Kb, const unsigned int* __restrict__ QV,
                          const float* __restrict__ Sb,
                          const int* __restrict__ row_start, const int* __restrict__ col,
                          float* __restrict__ H)
{
    const int tid = threadIdx.x;
    const int node = blockIdx.x * 2 + (tid >> 7);
    const int d = tid & 127;
    const float kd = Kb[(size_t)node * D + d];
    float acc = 0.f;
    const int e0 = row_start[node];
    const int e1 = row_start[node + 1];
    int e = e0;
    for (; e + 4 <= e1; e += 4) {
        const int s0 = col[e + 0];
        const int s1 = col[e + 1];
        const int s2 = col[e + 2];
        const int s3 = col[e + 3];
        const unsigned u0 = QV[(size_t)s0 * D + d];
        const unsigned u1 = QV[(size_t)s1 * D + d];
        const unsigned u2 = QV[(size_t)s2 * D + d];
        const unsigned u3 = QV[(size_t)s3 * D + d];
        const h16x2 a0 = __builtin_bit_cast(h16x2, u0);
        const h16x2 a1 = __builtin_bit_cast(h16x2, u1);
        const h16x2 a2 = __builtin_bit_cast(h16x2, u2);
        const h16x2 a3 = __builtin_bit_cast(h16x2, u3);
        acc = fmaf(fsigmoid(kd + (float)a0[0]), (float)a0[1], acc);
        acc = fmaf(fsigmoid(kd + (float)a1[0]), (float)a1[1], acc);
        acc = fmaf(fsigmoid(kd + (float)a2[0]), (float)a2[1], acc);
        acc = fmaf(fsigmoid(kd + (float)a3[0]), (float)a3[1], acc);
    }
    for (; e < e1; ++e) {
        const int s = col[e];
        const h16x2 a = __builtin_bit_cast(h16x2, QV[(size_t)s * D + d]);
        acc = fmaf(fsigmoid(kd + (float)a[0]), (float)a[1], acc);
    }
    H[(size_t)node * D + d] = fmaxf(acc + Sb[(size_t)node * D + d], 0.0f);
}

// ---------------- BatchNorm over nodes ----------------
__global__ void bn_stats(const float* __restrict__ H, float* __restrict__ fsum,
                         float* __restrict__ fsq)
{
    __shared__ float s1[256], s2[256];
    const int tid = threadIdx.x;
    const int d = tid & 127;
    const int rowoff = tid >> 7;
    float sum = 0.f, sq = 0.f;
    for (int n = blockIdx.x * 2 + rowoff; n < N_NODES; n += gridDim.x * 2) {
        const float v = H[(size_t)n * D + d];
        sum += v; sq += v * v;
    }
    s1[tid] = sum; s2[tid] = sq;
    __syncthreads();
    if (tid < 128) {
        atomicAdd(&fsum[d], s1[tid] + s1[tid + 128]);
        atomicAdd(&fsq[d],  s2[tid] + s2[tid + 128]);
    }
}

__global__ void bn_apply(float* __restrict__ H, const float* __restrict__ fsum,
                         const float* __restrict__ fsq, const float* __restrict__ g,
                         const float* __restrict__ b)
{
    const int idx = blockIdx.x * blockDim.x + threadIdx.x;
    const int total = N_NODES * D / 4;
    if (idx >= total) return;
    float4 h = ((const float4*)H)[idx];
    float hv[4] = {h.x, h.y, h.z, h.w};
    const int dbase = (idx * 4) & 127;
    float o[4];
    #pragma unroll
    for (int c = 0; c < 4; ++c) {
        const int d = dbase + c;
        const float mu = fsum[d] * (1.0f / N_NODES);
        const float var = fsq[d] * (1.0f / N_NODES) - mu * mu;
        const float sc = g[d] * rsqrtf(var + EPS);
        o[c] = (hv[c] - mu) * sc + b[d];
    }
    ((float4*)H)[idx] = make_float4(o[0], o[1], o[2], o[3]);
}

// ---------------- Pooling ----------------
__global__ void find_gstart(const int* __restrict__ batch, int* __restrict__ gstart) {
    const int g = threadIdx.x;
    if (g > N_GRAPHS) return;
    int lo = 0, hi = N_NODES;
    while (lo < hi) {
        int mid = (lo + hi) >> 1;
        if (batch[mid] < g) lo = mid + 1; else hi = mid;
    }
    gstart[g] = lo;
}

__global__ void pool_partial(const float* __restrict__ X, const int* __restrict__ gstart,
                             float* __restrict__ psum, float* __restrict__ pmax)
{
    const int g = blockIdx.x / PCHUNK;
    const int c = blockIdx.x % PCHUNK;
    const int d = threadIdx.x;
    const int lo = gstart[g], hi = gstart[g + 1];
    float sum = 0.f, mx = -INFINITY;
    for (int n = lo + c; n < hi; n += PCHUNK) {
        const float v = X[(size_t)n * D + d];
        sum += v;
        mx = fmaxf(mx, v);
    }
    psum[(size_t)blockIdx.x * D + d] = sum;
    pmax[(size_t)blockIdx.x * D + d] = mx;
}

__global__ void pool_combine(const float* __restrict__ psum, const float* __restrict__ pmax,
                             const int* __restrict__ gstart,
                             float* __restrict__ gap, float* __restrict__ gsp)
{
    const int g = blockIdx.x;
    const int d = threadIdx.x;
    float sum = 0.f, mx = -INFINITY;
    #pragma unroll
    for (int c = 0; c < PCHUNK; ++c) {
        sum += psum[(size_t)(g * PCHUNK + c) * D + d];
        mx = fmaxf(mx, pmax[(size_t)(g * PCHUNK + c) * D + d]);
    }
    const int cnt = gstart[g + 1] - gstart[g];
    gap[g * D + d] = sum / fmaxf((float)cnt, 1.0f);
    gsp[g * D + d] = (cnt > 0) ? mx : 0.0f;
}

// ---------------- BN over rows (small) ----------------
__global__ void bn_rows(const float* __restrict__ A, int rows, int cols,
                        const float* __restrict__ g, const float* __restrict__ b,
                        float* __restrict__ out, int out_cols, int out_off)
{
    const int c = blockIdx.x * blockDim.x + threadIdx.x;
    if (c >= cols) return;
    float sum = 0.f, sq = 0.f;
    for (int r = 0; r < rows; ++r) {
        const float v = A[r * cols + c];
        sum += v; sq += v * v;
    }
    const float mu = sum / rows;
    const float var = sq / rows - mu * mu;
    const float sc = g[c] * rsqrtf(var + EPS);
    const float sh = b[c] - mu * sc;
    for (int r = 0; r < rows; ++r) {
        out[r * out_cols + out_off + c] = A[r * cols + c] * sc + sh;
    }
}

// ---------------- small GEMM: out = [relu](A @ W + bias) ----------------
__global__ void gemm_small(const float* __restrict__ A, const float* __restrict__ W,
                           const float* __restrict__ bias, float* __restrict__ out,
                           int K, int C, int relu)
{
    __shared__ float as[256];
    const int r = blockIdx.x;
    for (int k = threadIdx.x; k < K; k += blockDim.x) as[k] = A[r * K + k];
    __syncthreads();
    const int j = threadIdx.x;
    if (j < C) {
        float acc = bias[j];
        for (int k = 0; k < K; ++k) acc = fmaf(as[k], W[k * C + j], acc);
        if (relu) acc = fmaxf(acc, 0.f);
        out[r * C + j] = acc;
    }
}

extern "C" void kernel_launch(void* const* d_in, const int* in_sizes, int n_in,
                              void* d_out, int out_size, void* d_ws, size_t ws_size,
                              hipStream_t stream)
{
    const float* x     = (const float*)d_in[0];
    const int*   ei    = (const int*)d_in[1];
    const int*   srcE  = ei;
    const int*   dstE  = ei + N_EDGES;
    const int*   batch = (const int*)d_in[2];
    const float* Wk = (const float*)d_in[3];  const float* bk = (const float*)d_in[4];
    const float* Wq = (const float*)d_in[5];  const float* bq = (const float*)d_in[6];
    const float* Wv = (const float*)d_in[7];  const float* bv = (const float*)d_in[8];
    const float* Ws = (const float*)d_in[9];  const float* bs = (const float*)d_in[10];
    const float* g_cl = (const float*)d_in[11]; const float* b_cl = (const float*)d_in[12];
    const float* g_gap = (const float*)d_in[13]; const float* b_gap = (const float*)d_in[14];
    const float* g_gsp = (const float*)d_in[15]; const float* b_gsp = (const float*)d_in[16];
    const float* W1 = (const float*)d_in[17]; const float* b1 = (const float*)d_in[18];
    const float* g1 = (const float*)d_in[19]; const float* bt1 = (const float*)d_in[20];
    const float* W2 = (const float*)d_in[21]; const float* b2 = (const float*)d_in[22];
    const float* g2 = (const float*)d_in[23]; const float* bt2 = (const float*)d_in[24];
    const float* Wl = (const float*)d_in[25]; const float* bl = (const float*)d_in[26];
    float* out = (float*)d_out;

    // ---- workspace carve ----
    char* ws = (char*)d_ws;
    size_t off = 0;
    const size_t bufB = (size_t)N_NODES * D * sizeof(float);   // 25.6 MB
    float* Kb = (float*)(ws + off); off = align256(off + bufB);
    unsigned short* QVh = (unsigned short*)(ws + off); off = align256(off + bufB); // half2 packed Q,V
    float* Sb = (float*)(ws + off); off = align256(off + bufB);
    float* H  = (float*)(ws + off); off = align256(off + bufB);
    unsigned short* Xhi = (unsigned short*)(ws + off); off = align256(off + (size_t)N_PAD * D * 2);
    unsigned short* Xlo = (unsigned short*)(ws + off); off = align256(off + (size_t)N_PAD * D * 2);
    unsigned short* Whi = (unsigned short*)(ws + off); off = align256(off + (size_t)12 * D * D * 2);
    unsigned short* Wlo = (unsigned short*)(ws + off); off = align256(off + (size_t)12 * D * D * 2);
    float* fsum = (float*)(ws + off); off = align256(off + 128 * sizeof(float));
    float* fsq  = (float*)(ws + off); off = align256(off + 128 * sizeof(float));
    int* cnt       = (int*)(ws + off); off = align256(off + (size_t)N_NODES * sizeof(int));
    int* row_start = (int*)(ws + off); off = align256(off + (size_t)(N_NODES + 1) * sizeof(int));
    int* cursor    = (int*)(ws + off); off = align256(off + (size_t)(N_NODES + 1) * sizeof(int));
    int* colI      = (int*)(ws + off); off = align256(off + (size_t)N_EDGES * sizeof(int));
    int* bsum      = (int*)(ws + off); off = align256(off + 256 * sizeof(int));
    int* boff      = (int*)(ws + off); off = align256(off + 256 * sizeof(int));
    int* gstart    = (int*)(ws + off); off = align256(off + (N_GRAPHS + 1) * sizeof(int));
    float* psum = (float*)(ws + off); off = align256(off + (size_t)N_GRAPHS * PCHUNK * D * sizeof(float));
    float* pmax = (float*)(ws + off); off = align256(off + (size_t)N_GRAPHS * PCHUNK * D * sizeof(float));
    float* gap = (float*)(ws + off); off = align256(off + (size_t)N_GRAPHS * D * sizeof(float));
    float* gsp = (float*)(ws + off); off = align256(off + (size_t)N_GRAPHS * D * sizeof(float));
    float* h0  = (float*)(ws + off); off = align256(off + (size_t)N_GRAPHS * 256 * sizeof(float));
    float* h1  = (float*)(ws + off); off = align256(off + (size_t)N_GRAPHS * 256 * sizeof(float));
    float* h2  = (float*)(ws + off); off = align256(off + (size_t)N_GRAPHS * 128 * sizeof(float));
    if (off > ws_size) return;

    // ---- one-time prep ----
    hipMemsetAsync(cnt, 0, (size_t)N_NODES * sizeof(int), stream);
    hist_dst<<<(N_EDGES + 255) / 256, 256, 0, stream>>>(dstE, cnt);
    scan_block_sums<<<SCAN_NB, 256, 0, stream>>>(cnt, bsum);
    scan_block_offsets<<<1, 256, 0, stream>>>(bsum, boff);
    scan_final<<<SCAN_NB, 256, 0, stream>>>(cnt, boff, row_start, cursor);
    fill_csr<<<(N_EDGES + 255) / 256, 256, 0, stream>>>(srcE, dstE, cursor, colI);
    find_gstart<<<1, 128, 0, stream>>>(batch, gstart);
    prep_w<<<12 * 128, 128, 0, stream>>>(Wk, Wq, Wv, Ws, Whi, Wlo);
    convert_split<<<(N_PAD * (D / 4) + 255) / 256, 256, 0, stream>>>(x, Xhi, Xlo);

    // ---- 3 conv layers ----
    for (int i = 0; i < 3; ++i) {
        gemm_kqvs_mfma<<<dim3(N_PAD / (16 * GSTRIPES), 2), 512, 0, stream>>>(
            Xhi, Xlo,
            Whi + (size_t)i * 4 * D * D, Wlo + (size_t)i * 4 * D * D,
            bk + i * D, bq + i * D, bv + i * D, bs + i * D,
            Kb, QVh, Sb);
        aggregate<<<N_NODES / 2, 256, 0, stream>>>(Kb, (const unsigned int*)QVh, Sb, row_start, colI, H);
        hipMemsetAsync(fsum, 0, 128 * sizeof(float), stream);
        hipMemsetAsync(fsq, 0, 128 * sizeof(float), stream);
        bn_stats<<<256, 256, 0, stream>>>(H, fsum, fsq);
        bn_apply<<<(N_NODES * D / 4 + 255) / 256, 256, 0, stream>>>(
            H, fsum, fsq, g_cl + i * D, b_cl + i * D);
        if (i < 2) {
            convert_split<<<(N_PAD * (D / 4) + 255) / 256, 256, 0, stream>>>(H, Xhi, Xlo);
        }
    }

    // ---- pooling ----
    pool_partial<<<N_GRAPHS * PCHUNK, 128, 0, stream>>>(H, gstart, psum, pmax);
    pool_combine<<<N_GRAPHS, 128, 0, stream>>>(psum, pmax, gstart, gap, gsp);
    bn_rows<<<1, 128, 0, stream>>>(gap, N_GRAPHS, 128, g_gap, b_gap, h0, 256, 0);
    bn_rows<<<1, 128, 0, stream>>>(gsp, N_GRAPHS, 128, g_gsp, b_gsp, h0, 256, 128);

    // ---- MLP head ----
    gemm_small<<<N_GRAPHS, 256, 0, stream>>>(h0, W1, b1, h1, 256, 256, 1);
    bn_rows<<<1, 256, 0, stream>>>(h1, N_GRAPHS, 256, g1, bt1, h1, 256, 0);
    gemm_small<<<N_GRAPHS, 256, 0, stream>>>(h1, W2, b2, h2, 256, 128, 1);
    bn_rows<<<1, 128, 0, stream>>>(h2, N_GRAPHS, 128, g2, bt2, h2, 128, 0);
    gemm_small<<<N_GRAPHS, 256, 0, stream>>>(h2, Wl, bl, out, 128, 5, 0);
}